// Round 5
// baseline (469.437 us; speedup 1.0000x reference)
//
#include <hip/hip_runtime.h>
#include <hip/hip_bf16.h>

typedef unsigned char u8;
typedef unsigned short u16;
typedef unsigned int u32;
typedef __attribute__((ext_vector_type(8))) short bf8;
typedef __attribute__((ext_vector_type(4))) float f4;

#define B_ 256
#define O_ 128
#define Hh_ 512
#define H_ 1024
#define DF_ 1536
#define I_ 2048

// ws layout (bytes)
#define XC_OFF    524288     // 256*4096 bf16 = 2097152
#define PRE_OFF   2621440    // 4 MB region: Epart 1 MB @ +0, hwePart 2 MB @ +1MB (attn phase)
                             // atomic-fallback pre (4 MB) reuses whole region after attn
#define HWEP_OFF  (PRE_OFF + 1048576)
#define FLAG_OFF  6815744    // flags ints; cnt[256] at +64 bytes
#define XJ16_OFF  7340032    // 16777216 bf16 = 33554432   [big-ws only]
#define UE16_OFF  40894464   // 262144 bf16 = 524288       [big-ws only]
#define WS_BIG    41418752
// big-ws only: gates partial buffer ALIASES xj16 region (last xj16 reader is
// the attn last-block phi, which completes before k_gates launches in-stream).
#define GPART_OFF XJ16_OFF   // 8 kc * 4 gates * 256*1024 f32 = 33554432

__device__ __forceinline__ float bf1(u16 u){ union{u32 i; float f;} v; v.i = ((u32)u)<<16; return v.f; }
__device__ __forceinline__ u16 f2bf(float f){
    __hip_bfloat16 h = __float2bfloat16(f);
    union{ __hip_bfloat16 h; u16 u; } v; v.h = h; return v.u;
}
__device__ __forceinline__ u32 pack2(float a, float b){
    return ((u32)f2bf(a)) | (((u32)f2bf(b))<<16);
}
struct P8 { uint4 lo, hi; };
__device__ __forceinline__ P8 fetch8(const void* p, size_t idx, int isf32){
    P8 r;
    if(isf32){
        const uint4* f = (const uint4*)((const float*)p + idx);
        r.lo = f[0]; r.hi = f[1];
    } else {
        r.lo = *(const uint4*)((const u16*)p + idx);
    }
    return r;
}
__device__ __forceinline__ uint4 cvt8(P8 r, int isf32){
    if(isf32){
        float4 x = *(float4*)&r.lo, y = *(float4*)&r.hi;
        uint4 o;
        o.x = pack2(x.x,x.y); o.y = pack2(x.z,x.w);
        o.z = pack2(y.x,y.y); o.w = pack2(y.z,y.w);
        return o;
    }
    return r.lo;
}
__device__ __forceinline__ uint4 load8(const void* p, size_t idx, int isf32){
    return cvt8(fetch8(p, idx, isf32), isf32);
}
__device__ __forceinline__ float loads(const void* p, size_t idx, int isf32){
    return isf32 ? ((const float*)p)[idx] : bf1(((const u16*)p)[idx]);
}
__device__ __forceinline__ float fast_tanh(float x){
    return 1.0f - 2.0f/(__expf(2.0f*x)+1.0f);
}
__device__ __forceinline__ float sigmoidf_(float x){
    return 1.0f/(1.0f+__expf(-x));
}

// ---------------- dtype detection + counter reset ----------------
__global__ void k_detect(const u8* __restrict__ m, const u16* __restrict__ xj,
                         int* __restrict__ flags, int* __restrict__ cnt){
    __shared__ int n1, n2, n3, mb, xo;
    int t = threadIdx.x;
    cnt[t] = 0;                      // zero the 256 per-b attn counters
    if(t==0){ n1=0; n2=0; n3=0; mb=0; xo=0; }
    __syncthreads();
    int a1=0, a2=0, a3=0, amax=0;
    for(int i=t; i<8192; i+=256){
        int v = m[i]; int c = i&3;
        if(c==1) a1|=v;
        if(c==2) a2|=v;
        if(c==3) a3|=v;
        amax = amax > v ? amax : v;
    }
    if(a1) atomicOr(&n1,1);
    if(a2) atomicOr(&n2,1);
    if(a3) atomicOr(&n3,1);
    atomicMax(&mb, amax);
    int e = 0;
    for(int i=t; i<2048; i+=256){
        u32 u = xj[2*i];
        int ex = (u>>7)&0xFF;
        if(ex >= 156) e = 1;
    }
    if(e) atomicOr(&xo,1);
    __syncthreads();
    if(t==0){
        int w;
        if(!n1 && !n2 && !n3)      w = 4;   // int32
        else if(!n1 && n2 && n3)   w = 4;   // f32
        else if(mb > 1)            w = 2;   // bf16
        else                       w = 1;   // bool8
        flags[0] = w;
        flags[1] = xo;
    }
}

// ---------------- merged prep: conv (big only) | hwe partials | pack ----------------
// grid: [0, convN)             -> conv xj->xj16 (8192 blocks) + Ue->ue16 (128 blocks)
//       [convN, convN+64)      -> hwe GEMM, grid (8 n, 4 kc, 2 m), K-chunk 256
//       [convN+64, +64+3584)   -> pack X_F|h|c into Xc[512:4096)
__global__ __launch_bounds__(256) void k_prep(const void* __restrict__ xj,
                                              const void* __restrict__ Ue,
                                              const void* __restrict__ XF,
                                              const void* __restrict__ h,
                                              const void* __restrict__ c,
                                              const void* __restrict__ We,
                                              const int* __restrict__ flags,
                                              int convN,
                                              u16* __restrict__ xj16,
                                              u16* __restrict__ ue16,
                                              float* __restrict__ hwePart,
                                              u16* __restrict__ Xc){
    int bid = blockIdx.x, t = threadIdx.x;
    int isf32 = flags[1];
    if(bid < convN){
        size_t g = (size_t)bid*256 + t;
        if(g < 2097152){
            size_t idx = g*8;
            *(uint4*)&xj16[idx] = load8(xj, idx, isf32);
        } else {
            size_t idx = (g - 2097152)*8;
            *(uint4*)&ue16[idx] = load8(Ue, idx, isf32);
        }
        return;
    }
    bid -= convN;
    if(bid < 64){
        // hwe: n = bid&7, kc = (bid>>3)&3, m = bid>>5
        int n0 = (bid&7)*64;
        int kb = ((bid>>3)&3)*256;
        int m0 = (bid>>5)*128;
        __shared__ __align__(16) u16 As[128*40];
        __shared__ __align__(16) u16 Bs[64*40];
        int w = t>>6, lane = t&63;
        int q = lane>>4, l16 = lane&15;
        int koff = q*8;
        f4 acc[2][4];
        for(int mi=0;mi<2;mi++) for(int ni=0;ni<4;ni++){
            f4 z = {0.f,0.f,0.f,0.f}; acc[mi][ni] = z;
        }
        for(int ks=0; ks<256; ks+=32){
            __syncthreads();
            for(int i=0;i<2;i++){
                int row = i*64 + (t>>2), cv = t&3;
                uint4 va = load8(h, (size_t)(m0+row)*H_ + kb + ks + cv*8, isf32);
                *(uint4*)&As[row*40 + cv*8] = va;
            }
            {
                int row = t>>2, cv = t&3;
                uint4 vb = load8(We, (size_t)(n0+row)*H_ + kb + ks + cv*8, isf32);
                *(uint4*)&Bs[row*40 + cv*8] = vb;
            }
            __syncthreads();
            bf8 af[2], bfr[4];
            for(int mi=0;mi<2;mi++) af[mi]  = *(const bf8*)&As[(w*32+mi*16+l16)*40 + koff];
            for(int ni=0;ni<4;ni++) bfr[ni] = *(const bf8*)&Bs[(ni*16+l16)*40 + koff];
            for(int mi=0;mi<2;mi++)
                for(int ni=0;ni<4;ni++)
                    acc[mi][ni] = __builtin_amdgcn_mfma_f32_16x16x32_bf16(af[mi], bfr[ni], acc[mi][ni], 0,0,0);
        }
        float* hp = hwePart + (size_t)((bid>>3)&3)*(B_*Hh_);
        for(int mi=0;mi<2;mi++){
            for(int r=0;r<4;r++){
                int brow = m0 + w*32 + mi*16 + q*4 + r;
                for(int ni=0;ni<4;ni++){
                    int ncol = n0 + ni*16 + l16;
                    hp[(size_t)brow*Hh_ + ncol] = acc[mi][ni][r];
                }
            }
        }
        return;
    }
    bid -= 64;
    {
        // pack: rchunk = bid%14, b = bid/14
        int b = bid/14;
        int r = (bid%14)*256 + t;   // 0..3583
        float v;
        if(r < DF_)            v = loads(XF, (size_t)b*DF_ + r, isf32);
        else if(r < DF_ + H_)  v = loads(h,  (size_t)b*H_ + (r - DF_), isf32);
        else                   v = loads(c,  (size_t)b*H_ + (r - DF_ - H_), isf32);
        Xc[(size_t)b*4096 + 512 + r] = f2bf(v);
    }
}

// ---------------- attention e-GEMM (grid 256 b x 8 nc) + last-block softmax/phi ----------------
__global__ __launch_bounds__(256) void k_attn(const void* __restrict__ xjA,
                                              const void* __restrict__ wvec,
                                              const void* __restrict__ UeA,
                                              const void* __restrict__ be,
                                              const float* __restrict__ hwePart,
                                              const void* __restrict__ maskp,
                                              const int* __restrict__ flags,
                                              int srcbf,
                                              float* __restrict__ Epart,
                                              u16* __restrict__ Xc,
                                              int* __restrict__ cnt){
    int b = blockIdx.x, nc = blockIdx.y, t = threadIdx.x;
    int isf = flags[1];               // for be/wvec (original inputs)
    int isA = srcbf ? 0 : isf;        // for xjA/UeA
    __shared__ __align__(16) u16 As[128*40];
    __shared__ __align__(16) u16 Bs[64*40];
    __shared__ float hwes[64];
    __shared__ float wvs[64];
    __shared__ float es[O_];
    __shared__ float as_[O_];
    __shared__ float red[2];
    __shared__ int lastf;

    if(t < 64){
        int col = nc*64 + t;
        float s = 0.f;
        #pragma unroll
        for(int p=0;p<4;p++) s += hwePart[(size_t)p*(B_*Hh_) + (size_t)b*Hh_ + col];
        hwes[t] = s + loads(be, col, isf);
        wvs[t]  = loads(wvec, col, isf);
    }

    const size_t xboff = (size_t)b*O_*Hh_;
    int w = t>>6, lane = t&63;
    int q = lane>>4, l16 = lane&15;
    int koff = q*8;
    int rA = t>>2, cA = t&3;          // A rows rA, rA+64; B row rA (0..63)

    f4 acc[2][4];
    for(int mi=0;mi<2;mi++) for(int ni=0;ni<4;ni++){
        f4 z = {0.f,0.f,0.f,0.f}; acc[mi][ni] = z;
    }

    P8 pa0, pa1, pb;
    pa0 = fetch8(xjA, xboff + (size_t)rA*Hh_      + cA*8, isA);
    pa1 = fetch8(xjA, xboff + (size_t)(rA+64)*Hh_ + cA*8, isA);
    pb  = fetch8(UeA, (size_t)(nc*64 + rA)*Hh_    + cA*8, isA);

    for(int ks=0; ks<Hh_; ks+=32){
        __syncthreads();
        *(uint4*)&As[rA*40 + cA*8]      = cvt8(pa0, isA);
        *(uint4*)&As[(rA+64)*40 + cA*8] = cvt8(pa1, isA);
        *(uint4*)&Bs[rA*40 + cA*8]      = cvt8(pb, isA);
        __syncthreads();
        if(ks + 32 < Hh_){
            int kn = ks + 32;
            pa0 = fetch8(xjA, xboff + (size_t)rA*Hh_      + kn + cA*8, isA);
            pa1 = fetch8(xjA, xboff + (size_t)(rA+64)*Hh_ + kn + cA*8, isA);
            pb  = fetch8(UeA, (size_t)(nc*64 + rA)*Hh_    + kn + cA*8, isA);
        }
        bf8 af[2], bfr[4];
        for(int mi=0;mi<2;mi++) af[mi]  = *(const bf8*)&As[(w*32+mi*16+l16)*40 + koff];
        for(int ni=0;ni<4;ni++) bfr[ni] = *(const bf8*)&Bs[(ni*16+l16)*40 + koff];
        for(int mi=0;mi<2;mi++)
            for(int ni=0;ni<4;ni++)
                acc[mi][ni] = __builtin_amdgcn_mfma_f32_16x16x32_bf16(af[mi], bfr[ni], acc[mi][ni], 0,0,0);
    }
    // e epilogue: each wave owns disjoint o-rows -> plain stores
    for(int mi=0;mi<2;mi++){
        for(int r=0;r<4;r++){
            int o = w*32 + mi*16 + q*4 + r;
            float part = 0.f;
            for(int ni=0;ni<4;ni++){
                int col = ni*16 + l16;
                part += wvs[col] * fast_tanh(hwes[col] + acc[mi][ni][r]);
            }
            part += __shfl_xor(part, 1);
            part += __shfl_xor(part, 2);
            part += __shfl_xor(part, 4);
            part += __shfl_xor(part, 8);
            if(l16 == 0) Epart[(size_t)nc*32768 + (size_t)b*O_ + o] = part;
        }
    }

    // ---- last nc-block for this b does softmax + phi ----
    __threadfence();          // make Epart stores device-visible (release)
    __syncthreads();
    if(t==0) lastf = (atomicAdd(&cnt[b], 1) == 7);
    __syncthreads();
    if(!lastf) return;
    __threadfence();          // acquire: see the other 7 blocks' Epart

    int mw = flags[0];
    if(t < O_){
        float e = 0.f;
        #pragma unroll
        for(int p=0;p<8;p++) e += Epart[(size_t)p*32768 + (size_t)b*O_ + t];
        size_t mi_ = (size_t)b*O_ + t;
        bool valid;
        if(mw == 1)      valid = ((const u8*)maskp)[mi_]  != 0;
        else if(mw == 2) valid = ((const u16*)maskp)[mi_] != 0;
        else             valid = ((const u32*)maskp)[mi_] != 0;
        es[t] = valid ? e : -1e30f;
    }
    __syncthreads();
    if(t < 64){
        float v = fmaxf(es[t], es[t+64]);
        for(int m=32;m>0;m>>=1) v = fmaxf(v, __shfl_xor(v, m));
        if(t==0) red[0] = v;
    }
    __syncthreads();
    if(t < O_) as_[t] = __expf(es[t] - red[0]);
    __syncthreads();
    if(t < 64){
        float v = as_[t] + as_[t+64];
        for(int m=32;m>0;m>>=1) v += __shfl_xor(v, m);
        if(t==0) red[1] = v;
    }
    __syncthreads();
    float inv = 1.0f / red[1];
    // phi: thread t handles cols 2t, 2t+1 (xj tile is L2-hot from phase A)
    int c0 = 2*t;
    float a0 = 0.f, a1 = 0.f;
    if(isA == 0){
        const u16* xp = (const u16*)xjA + xboff + c0;
        #pragma unroll 8
        for(int o=0;o<O_;o++){
            u32 v = *(const u32*)(xp + (size_t)o*Hh_);
            a0 += as_[o] * bf1((u16)(v & 0xffff));
            a1 += as_[o] * bf1((u16)(v >> 16));
        }
    } else {
        const float* xp = (const float*)xjA + xboff + c0;
        #pragma unroll 8
        for(int o=0;o<O_;o++){
            float2 v = *(const float2*)(xp + (size_t)o*Hh_);
            a0 += as_[o] * v.x;
            a1 += as_[o] * v.y;
        }
    }
    Xc[(size_t)b*4096 + c0]     = f2bf(a0 * inv);
    Xc[(size_t)b*4096 + c0 + 1] = f2bf(a1 * inv);
}

// ---------------- gates GEMM, K-split: grid (64 nt, 8 kc of 512), 512 thr, BK=32 ----------------
__global__ __launch_bounds__(512) void k_gates(const u16* __restrict__ Xc,
    const void* __restrict__ Wi, const void* __restrict__ Wf, const void* __restrict__ Wc, const void* __restrict__ Wo,
    const void* __restrict__ Ui, const void* __restrict__ Uf, const void* __restrict__ Uc, const void* __restrict__ Uo,
    const void* __restrict__ Vi, const void* __restrict__ Vf, const void* __restrict__ Vo,
    const int* __restrict__ flags,
    int dosplit,
    float* __restrict__ part){
    int nt = blockIdx.x;          // gate g = nt>>4, n-tile nt&15
    int kc = blockIdx.y;          // K-chunk of 512
    int g  = nt>>4;
    int k0 = kc*512;
    if(g == 2 && k0 >= 3072) return; // c-gate has no V peephole
    int isf32 = flags[1];
    const void* Wm = (g==0)?Wi:(g==1)?Wf:(g==2)?Wc:Wo;
    const void* Um = (g==0)?Ui:(g==1)?Uf:(g==2)?Uc:Uo;
    const void* Vm = (g==0)?Vi:(g==1)?Vf:(g==3)?Vo:Vi;  // g==2 never dereferences V
    int n0 = (nt&15)*64;
    int t = threadIdx.x;
    __shared__ __align__(16) u16 As[256*40];
    __shared__ __align__(16) u16 Bs[64*40];
    int w = t>>6, lane = t&63;
    int q = lane>>4, l16 = lane&15;
    int koff = q*8;
    int rA = t>>2, cA = t&3;      // A rows rA, rA+128 (rA 0..127); B row rA if t<256
    bool hasB = (t < 256);

    f4 acc[2][4];
    for(int mi=0;mi<2;mi++) for(int ni=0;ni<4;ni++){
        f4 z = {0.f,0.f,0.f,0.f}; acc[mi][ni] = z;
    }

    auto fetchB = [&](int k)->P8{
        int n = n0 + rA;
        if(k < 2048)       return fetch8(Wm, (size_t)n*I_ + k, isf32);
        else if(k < 3072)  return fetch8(Um, (size_t)n*H_ + (k-2048), isf32);
        else               return fetch8(Vm, (size_t)n*H_ + (k-3072), isf32);
    };

    uint4 qa0, qa1; P8 qb;
    qa0 = *(const uint4*)(Xc + (size_t)rA*4096       + k0 + cA*8);
    qa1 = *(const uint4*)(Xc + (size_t)(rA+128)*4096 + k0 + cA*8);
    if(hasB) qb = fetchB(k0 + cA*8);

    for(int ks=0; ks<512; ks+=32){
        __syncthreads();
        *(uint4*)&As[rA*40 + cA*8]       = qa0;
        *(uint4*)&As[(rA+128)*40 + cA*8] = qa1;
        if(hasB) *(uint4*)&Bs[rA*40 + cA*8] = cvt8(qb, isf32);
        __syncthreads();
        if(ks + 32 < 512){
            int kn = k0 + ks + 32;
            qa0 = *(const uint4*)(Xc + (size_t)rA*4096       + kn + cA*8);
            qa1 = *(const uint4*)(Xc + (size_t)(rA+128)*4096 + kn + cA*8);
            if(hasB) qb = fetchB(kn + cA*8);
        }
        bf8 af[2], bfr[4];
        for(int mi=0;mi<2;mi++) af[mi]  = *(const bf8*)&As[(w*32+mi*16+l16)*40 + koff];
        for(int ni=0;ni<4;ni++) bfr[ni] = *(const bf8*)&Bs[(ni*16+l16)*40 + koff];
        for(int mi=0;mi<2;mi++)
            for(int ni=0;ni<4;ni++)
                acc[mi][ni] = __builtin_amdgcn_mfma_f32_16x16x32_bf16(af[mi], bfr[ni], acc[mi][ni], 0,0,0);
    }
    float* pg = dosplit ? (part + ((size_t)kc*4 + g)*(size_t)(B_*H_))
                        : (part + (size_t)g*(B_*H_));
    for(int mi=0;mi<2;mi++){
        for(int r=0;r<4;r++){
            int brow = w*32 + mi*16 + q*4 + r;
            for(int ni=0;ni<4;ni++){
                int ncol = n0 + ni*16 + l16;
                size_t o = (size_t)brow*H_ + ncol;
                if(dosplit) pg[o] = acc[mi][ni][r];
                else        atomicAdd(&pg[o], acc[mi][ni][r]);
            }
        }
    }
}

// ---------------- combine: sum kc partials + f32 outputs ----------------
__global__ __launch_bounds__(256) void k_combine(const float* __restrict__ part,
    int nsplit, int climit,
    const void* __restrict__ c,
    const void* __restrict__ bi, const void* __restrict__ bfv,
    const void* __restrict__ bc, const void* __restrict__ bo,
    const int* __restrict__ flags,
    float* __restrict__ out){
    int b = blockIdx.x, t = threadIdx.x;
    int isf32 = flags[1];
    const size_t G = (size_t)B_*H_;
    for(int i=0;i<4;i++){
        int n = i*256 + t;
        size_t idx = (size_t)b*H_ + n;
        float pi = 0.f, pf = 0.f, pcv = 0.f, po = 0.f;
        for(int p=0;p<nsplit;p++){
            const float* pp = part + (size_t)p*4*G;
            pi += pp[idx];
            pf += pp[G + idx];
            po += pp[3*G + idx];
            if(p < climit) pcv += pp[2*G + idx];
        }
        pi  += loads(bi,  n, isf32);
        pf  += loads(bfv, n, isf32);
        pcv += loads(bc,  n, isf32);
        po  += loads(bo,  n, isf32);
        float ig = sigmoidf_(pi);
        float fg = sigmoidf_(pf);
        float og = sigmoidf_(po);
        float cold = loads(c, idx, isf32);
        float ncv = fg*cold + ig*fast_tanh(pcv);
        float nh  = og*fast_tanh(ncv);
        out[idx]     = nh;    // new_h
        out[G + idx] = ncv;   // new_c
    }
}

extern "C" void kernel_launch(void* const* d_in, const int* in_sizes, int n_in,
                              void* d_out, int out_size, void* d_ws, size_t ws_size,
                              hipStream_t stream){
    const void* xj   = d_in[0];
    const void* mask = d_in[1];
    const void* XF   = d_in[2];
    const void* h    = d_in[3];
    const void* c    = d_in[4];
    const void* Wi   = d_in[5];
    const void* Wf   = d_in[6];
    const void* Wc   = d_in[7];
    const void* Wo   = d_in[8];
    const void* Ui   = d_in[9];
    const void* Uf   = d_in[10];
    const void* Uc   = d_in[11];
    const void* Uo   = d_in[12];
    const void* Vi   = d_in[13];
    const void* Vf   = d_in[14];
    // d_in[15] = V_c : unused by the reference
    const void* Vo   = d_in[16];
    const void* bi   = d_in[17];
    const void* bfv  = d_in[18];
    const void* bc   = d_in[19];
    const void* bo   = d_in[20];
    const void* wv   = d_in[21];
    const void* We   = d_in[22];
    const void* Ue   = d_in[23];
    const void* be   = d_in[24];

    char* ws = (char*)d_ws;
    u16*   Xc    = (u16*)(ws + XC_OFF);
    float* Epart = (float*)(ws + PRE_OFF);
    float* hweP  = (float*)(ws + HWEP_OFF);
    float* pre   = (float*)(ws + PRE_OFF);    // fallback atomic buffer (after attn)
    int*   flags = (int*)(ws + FLAG_OFF);
    int*   cnt   = (int*)(ws + FLAG_OFF + 64);
    float* out   = (float*)d_out;

    int big = (ws_size >= (size_t)WS_BIG);
    u16* xj16 = (u16*)(ws + XJ16_OFF);
    u16* ue16 = (u16*)(ws + UE16_OFF);
    float* gpart = (float*)(ws + GPART_OFF);   // aliases xj16 (safe after attn)
    const void* xjA = big ? (const void*)xj16 : xj;
    const void* UeA = big ? (const void*)ue16 : Ue;

    k_detect<<<1, 256, 0, stream>>>((const u8*)mask, (const u16*)xj, flags, cnt);
    int convN = big ? 8320 : 0;
    k_prep<<<convN + 64 + 3584, 256, 0, stream>>>(xj, Ue, XF, h, c, We, flags, convN,
                                                  xj16, ue16, hweP, Xc);
    k_attn<<<dim3(B_, 8), 256, 0, stream>>>(xjA, wv, UeA, be, hweP, mask, flags, big,
                                            Epart, Xc, cnt);
    if(big){
        k_gates<<<dim3(64, 8), 512, 0, stream>>>(Xc, Wi,Wf,Wc,Wo, Ui,Uf,Uc,Uo, Vi,Vf,Vo, flags, 1, gpart);
        k_combine<<<B_, 256, 0, stream>>>(gpart, 8, 6, c, bi, bfv, bc, bo, flags, out);
    } else {
        hipMemsetAsync(pre, 0, (size_t)4*B_*H_*sizeof(float), stream);
        k_gates<<<dim3(64, 8), 512, 0, stream>>>(Xc, Wi,Wf,Wc,Wo, Ui,Uf,Uc,Uo, Vi,Vf,Vo, flags, 0, pre);
        k_combine<<<B_, 256, 0, stream>>>(pre, 1, 1, c, bi, bfv, bc, bo, flags, out);
    }
}

// Round 7
// 303.951 us; speedup vs baseline: 1.5444x; 1.5444x over previous
//
#include <hip/hip_runtime.h>
#include <hip/hip_bf16.h>

typedef unsigned char u8;
typedef unsigned short u16;
typedef unsigned int u32;
typedef __attribute__((ext_vector_type(8))) short bf8;
typedef __attribute__((ext_vector_type(4))) float f4;

#define B_ 256
#define O_ 128
#define Hh_ 512
#define H_ 1024
#define DF_ 1536
#define I_ 2048

// ws layout (bytes)
#define HWE_OFF   0          // 256*512 f32 = 524288
#define XC_OFF    524288     // 256*4096 bf16 = 2097152
#define PRE_OFF   2621440    // 4 MB: Epart (1 MB) during attn; atomic-fallback pre
#define FLAG_OFF  6815744    // ints
#define XJ16_OFF  7340032    // 32 MB region [big-ws only] — now ONLY gpart
#define UE16_OFF  40894464   // 262144 bf16 = 524288       [big-ws only]
#define WS_BIG    41418752
#define GPART_OFF XJ16_OFF   // 8 kc * 4 gates * 256*1024 f32 = 33554432

__device__ __forceinline__ float bf1(u16 u){ union{u32 i; float f;} v; v.i = ((u32)u)<<16; return v.f; }
__device__ __forceinline__ u16 f2bf(float f){
    __hip_bfloat16 h = __float2bfloat16(f);
    union{ __hip_bfloat16 h; u16 u; } v; v.h = h; return v.u;
}
__device__ __forceinline__ u32 pack2(float a, float b){
    return ((u32)f2bf(a)) | (((u32)f2bf(b))<<16);
}
struct P8 { uint4 lo, hi; };
__device__ __forceinline__ P8 fetch8(const void* p, size_t idx, int isf32){
    P8 r;
    if(isf32){
        const uint4* f = (const uint4*)((const float*)p + idx);
        r.lo = f[0]; r.hi = f[1];
    } else {
        r.lo = *(const uint4*)((const u16*)p + idx);
    }
    return r;
}
__device__ __forceinline__ uint4 cvt8(P8 r, int isf32){
    if(isf32){
        float4 x = *(float4*)&r.lo, y = *(float4*)&r.hi;
        uint4 o;
        o.x = pack2(x.x,x.y); o.y = pack2(x.z,x.w);
        o.z = pack2(y.x,y.y); o.w = pack2(y.z,y.w);
        return o;
    }
    return r.lo;
}
__device__ __forceinline__ uint4 load8(const void* p, size_t idx, int isf32){
    return cvt8(fetch8(p, idx, isf32), isf32);
}
__device__ __forceinline__ float loads(const void* p, size_t idx, int isf32){
    return isf32 ? ((const float*)p)[idx] : bf1(((const u16*)p)[idx]);
}
__device__ __forceinline__ float fast_tanh(float x){
    return 1.0f - 2.0f/(__expf(2.0f*x)+1.0f);
}
__device__ __forceinline__ float sigmoidf_(float x){
    return 1.0f/(1.0f+__expf(-x));
}

// ---------------- dtype detection ----------------
__global__ void k_detect(const u8* __restrict__ m, const u16* __restrict__ xj,
                         int* __restrict__ flags){
    __shared__ int n1, n2, n3, mb, xo;
    int t = threadIdx.x;
    if(t==0){ n1=0; n2=0; n3=0; mb=0; xo=0; }
    __syncthreads();
    int a1=0, a2=0, a3=0, amax=0;
    for(int i=t; i<8192; i+=256){
        int v = m[i]; int c = i&3;
        if(c==1) a1|=v;
        if(c==2) a2|=v;
        if(c==3) a3|=v;
        amax = amax > v ? amax : v;
    }
    if(a1) atomicOr(&n1,1);
    if(a2) atomicOr(&n2,1);
    if(a3) atomicOr(&n3,1);
    atomicMax(&mb, amax);
    int e = 0;
    for(int i=t; i<2048; i+=256){
        u32 u = xj[2*i];
        int ex = (u>>7)&0xFF;
        if(ex >= 156) e = 1;
    }
    if(e) atomicOr(&xo,1);
    __syncthreads();
    if(t==0){
        int w;
        if(!n1 && !n2 && !n3)      w = 4;   // int32
        else if(!n1 && n2 && n3)   w = 4;   // f32
        else if(mb > 1)            w = 2;   // bf16
        else                       w = 1;   // bool8
        flags[0] = w;
        flags[1] = xo;
    }
}

// ---------------- pack X_F | h | c into Xc[512:4096) + Ue->ue16 conversion ----------------
// grid: [0, 3584*? ) pack role; [packN, packN+ueN) ue conversion (big only)
__global__ __launch_bounds__(256) void k_pack(const void* __restrict__ XF,
                                              const void* __restrict__ h,
                                              const void* __restrict__ c,
                                              const void* __restrict__ Ue,
                                              const int* __restrict__ flags,
                                              int packN,
                                              u16* __restrict__ Xc,
                                              u16* __restrict__ ue16){
    int bid = blockIdx.x, t = threadIdx.x;
    int isf32 = flags[1];
    if(bid < packN){
        int b = bid/14;
        int r = (bid%14)*256 + t;   // 0..3583
        float v;
        if(r < DF_)            v = loads(XF, (size_t)b*DF_ + r, isf32);
        else if(r < DF_ + H_)  v = loads(h,  (size_t)b*H_ + (r - DF_), isf32);
        else                   v = loads(c,  (size_t)b*H_ + (r - DF_ - H_), isf32);
        Xc[(size_t)b*4096 + 512 + r] = f2bf(v);
    } else {
        size_t g = (size_t)(bid - packN)*256 + t;   // 0..65535
        size_t idx = g*8;                            // 524288 elems
        *(uint4*)&ue16[idx] = load8(Ue, idx, isf32);
    }
}

// ---------------- hwe GEMM, K-split: grid (8 n, 8 kc, 2 m), 256 thr, atomics ----------------
__global__ __launch_bounds__(256) void k_hwe(const void* __restrict__ h,
                                             const void* __restrict__ We,
                                             const int* __restrict__ flags,
                                             float* __restrict__ hwe){
    int n0 = blockIdx.x*64;
    int kc = blockIdx.y*128;
    int m0 = blockIdx.z*128;
    int t = threadIdx.x;
    int isf32 = flags[1];
    __shared__ __align__(16) u16 As[128*40];
    __shared__ __align__(16) u16 Bs[64*40];
    int w = t>>6, lane = t&63;
    int q = lane>>4, l16 = lane&15;
    int koff = q*8;
    f4 acc[2][4];
    for(int mi=0;mi<2;mi++) for(int ni=0;ni<4;ni++){
        f4 z = {0.f,0.f,0.f,0.f}; acc[mi][ni] = z;
    }
    for(int ks=0; ks<128; ks+=32){
        __syncthreads();
        for(int i=0;i<2;i++){
            int row = i*64 + (t>>2), cv = t&3;
            uint4 va = load8(h, (size_t)(m0+row)*H_ + kc + ks + cv*8, isf32);
            *(uint4*)&As[row*40 + cv*8] = va;
        }
        {
            int row = t>>2, cv = t&3;
            uint4 vb = load8(We, (size_t)(n0+row)*H_ + kc + ks + cv*8, isf32);
            *(uint4*)&Bs[row*40 + cv*8] = vb;
        }
        __syncthreads();
        bf8 af[2], bfr[4];
        for(int mi=0;mi<2;mi++) af[mi]  = *(const bf8*)&As[(w*32+mi*16+l16)*40 + koff];
        for(int ni=0;ni<4;ni++) bfr[ni] = *(const bf8*)&Bs[(ni*16+l16)*40 + koff];
        for(int mi=0;mi<2;mi++)
            for(int ni=0;ni<4;ni++)
                acc[mi][ni] = __builtin_amdgcn_mfma_f32_16x16x32_bf16(af[mi], bfr[ni], acc[mi][ni], 0,0,0);
    }
    for(int mi=0;mi<2;mi++){
        for(int r=0;r<4;r++){
            int brow = m0 + w*32 + mi*16 + q*4 + r;
            for(int ni=0;ni<4;ni++){
                int ncol = n0 + ni*16 + l16;
                atomicAdd(&hwe[(size_t)brow*Hh_ + ncol], acc[mi][ni][r]);
            }
        }
    }
}

// ---------------- attention e-score GEMM: grid (256 b, 8 n-tiles of 64), 256 thr ----------------
// A (xj) read RAW (f32 or bf16 per isf); B (Ue) from bf16 master copy when available.
__global__ __launch_bounds__(256) void k_attn(const void* __restrict__ xjA,
                                              const void* __restrict__ wvec,
                                              const void* __restrict__ UeA,
                                              const void* __restrict__ be,
                                              const float* __restrict__ hwe,
                                              const int* __restrict__ flags,
                                              int srcbfB,
                                              float* __restrict__ Epart){
    int b = blockIdx.x, nc = blockIdx.y, t = threadIdx.x;
    int isf = flags[1];               // for be/wvec/xjA (original inputs)
    int isA = isf;                    // xj is always the raw input
    int isB = srcbfB ? 0 : isf;       // UeA (bf16 master when big-ws)
    __shared__ __align__(16) u16 As[128*40];
    __shared__ __align__(16) u16 Bs[64*40];
    __shared__ float hwes[64];
    __shared__ float wvs[64];

    if(t < 64){
        int col = nc*64 + t;
        hwes[t] = hwe[(size_t)b*Hh_ + col] + loads(be, col, isf);
        wvs[t]  = loads(wvec, col, isf);
    }

    const size_t xboff = (size_t)b*O_*Hh_;
    int w = t>>6, lane = t&63;
    int q = lane>>4, l16 = lane&15;
    int koff = q*8;
    int rA = t>>2, cA = t&3;          // A rows rA, rA+64; B row rA (0..63)

    f4 acc[2][4];
    for(int mi=0;mi<2;mi++) for(int ni=0;ni<4;ni++){
        f4 z = {0.f,0.f,0.f,0.f}; acc[mi][ni] = z;
    }

    P8 pa0, pa1, pb;
    pa0 = fetch8(xjA, xboff + (size_t)rA*Hh_      + cA*8, isA);
    pa1 = fetch8(xjA, xboff + (size_t)(rA+64)*Hh_ + cA*8, isA);
    pb  = fetch8(UeA, (size_t)(nc*64 + rA)*Hh_    + cA*8, isB);

    for(int ks=0; ks<Hh_; ks+=32){
        __syncthreads();
        *(uint4*)&As[rA*40 + cA*8]      = cvt8(pa0, isA);
        *(uint4*)&As[(rA+64)*40 + cA*8] = cvt8(pa1, isA);
        *(uint4*)&Bs[rA*40 + cA*8]      = cvt8(pb, isB);
        __syncthreads();
        if(ks + 32 < Hh_){
            int kn = ks + 32;
            pa0 = fetch8(xjA, xboff + (size_t)rA*Hh_      + kn + cA*8, isA);
            pa1 = fetch8(xjA, xboff + (size_t)(rA+64)*Hh_ + kn + cA*8, isA);
            pb  = fetch8(UeA, (size_t)(nc*64 + rA)*Hh_    + kn + cA*8, isB);
        }
        bf8 af[2], bfr[4];
        for(int mi=0;mi<2;mi++) af[mi]  = *(const bf8*)&As[(w*32+mi*16+l16)*40 + koff];
        for(int ni=0;ni<4;ni++) bfr[ni] = *(const bf8*)&Bs[(ni*16+l16)*40 + koff];
        for(int mi=0;mi<2;mi++)
            for(int ni=0;ni<4;ni++)
                acc[mi][ni] = __builtin_amdgcn_mfma_f32_16x16x32_bf16(af[mi], bfr[ni], acc[mi][ni], 0,0,0);
    }
    // epilogue: each wave owns disjoint o-rows -> plain stores, no atomics
    for(int mi=0;mi<2;mi++){
        for(int r=0;r<4;r++){
            int o = w*32 + mi*16 + q*4 + r;
            float part = 0.f;
            for(int ni=0;ni<4;ni++){
                int col = ni*16 + l16;
                part += wvs[col] * fast_tanh(hwes[col] + acc[mi][ni][r]);
            }
            part += __shfl_xor(part, 1);
            part += __shfl_xor(part, 2);
            part += __shfl_xor(part, 4);
            part += __shfl_xor(part, 8);
            if(l16 == 0) Epart[(size_t)nc*32768 + (size_t)b*O_ + o] = part;
        }
    }
}

// ---------------- softmax + phi: grid 256 (per b), 512 thr ----------------
__global__ __launch_bounds__(512) void k_soft(const float* __restrict__ Epart,
                                              const void* __restrict__ maskp,
                                              const void* __restrict__ xjA,
                                              const int* __restrict__ flags,
                                              u16* __restrict__ Xc){
    int b = blockIdx.x, t = threadIdx.x;
    int isf = flags[1];
    int isA = isf;                    // xj is always the raw input
    int mw = flags[0];
    __shared__ float es[O_];
    __shared__ float as_[O_];
    __shared__ float red[2];
    if(t < O_){
        float e = 0.f;
        for(int p=0;p<8;p++) e += Epart[(size_t)p*32768 + (size_t)b*O_ + t];
        size_t mi_ = (size_t)b*O_ + t;
        bool valid;
        if(mw == 1)      valid = ((const u8*)maskp)[mi_]  != 0;
        else if(mw == 2) valid = ((const u16*)maskp)[mi_] != 0;
        else             valid = ((const u32*)maskp)[mi_] != 0;
        es[t] = valid ? e : -1e30f;
    }
    __syncthreads();
    if(t < 64){
        float v = fmaxf(es[t], es[t+64]);
        for(int m=32;m>0;m>>=1) v = fmaxf(v, __shfl_xor(v, m));
        if(t==0) red[0] = v;
    }
    __syncthreads();
    if(t < O_) as_[t] = __expf(es[t] - red[0]);
    __syncthreads();
    if(t < 64){
        float v = as_[t] + as_[t+64];
        for(int m=32;m>0;m>>=1) v += __shfl_xor(v, m);
        if(t==0) red[1] = v;
    }
    __syncthreads();
    float inv = 1.0f / red[1];
    float acc = 0.f;
    size_t base = (size_t)b*O_*Hh_ + t;
    #pragma unroll 8
    for(int o=0;o<O_;o++){
        acc += as_[o] * loads(xjA, base + (size_t)o*Hh_, isA);
    }
    Xc[(size_t)b*4096 + t] = f2bf(acc * inv);
}

// ---------------- gates GEMM, K-split: grid (64 nt, 8 kc of 512), 512 thr, BK=32 ----------------
__global__ __launch_bounds__(512) void k_gates(const u16* __restrict__ Xc,
    const void* __restrict__ Wi, const void* __restrict__ Wf, const void* __restrict__ Wc, const void* __restrict__ Wo,
    const void* __restrict__ Ui, const void* __restrict__ Uf, const void* __restrict__ Uc, const void* __restrict__ Uo,
    const void* __restrict__ Vi, const void* __restrict__ Vf, const void* __restrict__ Vo,
    const int* __restrict__ flags,
    int dosplit,
    float* __restrict__ part){
    int nt = blockIdx.x;          // gate g = nt>>4, n-tile nt&15
    int kc = blockIdx.y;          // K-chunk of 512
    int g  = nt>>4;
    int k0 = kc*512;
    if(g == 2 && k0 >= 3072) return; // c-gate has no V peephole
    int isf32 = flags[1];
    const void* Wm = (g==0)?Wi:(g==1)?Wf:(g==2)?Wc:Wo;
    const void* Um = (g==0)?Ui:(g==1)?Uf:(g==2)?Uc:Uo;
    const void* Vm = (g==0)?Vi:(g==1)?Vf:(g==3)?Vo:Vi;  // g==2 never dereferences V
    int n0 = (nt&15)*64;
    int t = threadIdx.x;
    __shared__ __align__(16) u16 As[256*40];
    __shared__ __align__(16) u16 Bs[64*40];
    int w = t>>6, lane = t&63;
    int q = lane>>4, l16 = lane&15;
    int koff = q*8;
    int rA = t>>2, cA = t&3;      // A rows rA, rA+128 (rA 0..127); B row rA if t<256
    bool hasB = (t < 256);

    f4 acc[2][4];
    for(int mi=0;mi<2;mi++) for(int ni=0;ni<4;ni++){
        f4 z = {0.f,0.f,0.f,0.f}; acc[mi][ni] = z;
    }

    auto fetchB = [&](int k)->P8{
        int n = n0 + rA;
        if(k < 2048)       return fetch8(Wm, (size_t)n*I_ + k, isf32);
        else if(k < 3072)  return fetch8(Um, (size_t)n*H_ + (k-2048), isf32);
        else               return fetch8(Vm, (size_t)n*H_ + (k-3072), isf32);
    };

    uint4 qa0, qa1; P8 qb;
    qa0 = *(const uint4*)(Xc + (size_t)rA*4096       + k0 + cA*8);
    qa1 = *(const uint4*)(Xc + (size_t)(rA+128)*4096 + k0 + cA*8);
    if(hasB) qb = fetchB(k0 + cA*8);

    for(int ks=0; ks<512; ks+=32){
        __syncthreads();
        *(uint4*)&As[rA*40 + cA*8]       = qa0;
        *(uint4*)&As[(rA+128)*40 + cA*8] = qa1;
        if(hasB) *(uint4*)&Bs[rA*40 + cA*8] = cvt8(qb, isf32);
        __syncthreads();
        if(ks + 32 < 512){
            int kn = k0 + ks + 32;
            qa0 = *(const uint4*)(Xc + (size_t)rA*4096       + kn + cA*8);
            qa1 = *(const uint4*)(Xc + (size_t)(rA+128)*4096 + kn + cA*8);
            if(hasB) qb = fetchB(kn + cA*8);
        }
        bf8 af[2], bfr[4];
        for(int mi=0;mi<2;mi++) af[mi]  = *(const bf8*)&As[(w*32+mi*16+l16)*40 + koff];
        for(int ni=0;ni<4;ni++) bfr[ni] = *(const bf8*)&Bs[(ni*16+l16)*40 + koff];
        for(int mi=0;mi<2;mi++)
            for(int ni=0;ni<4;ni++)
                acc[mi][ni] = __builtin_amdgcn_mfma_f32_16x16x32_bf16(af[mi], bfr[ni], acc[mi][ni], 0,0,0);
    }
    float* pg = dosplit ? (part + ((size_t)kc*4 + g)*(size_t)(B_*H_))
                        : (part + (size_t)g*(B_*H_));
    for(int mi=0;mi<2;mi++){
        for(int r=0;r<4;r++){
            int brow = w*32 + mi*16 + q*4 + r;
            for(int ni=0;ni<4;ni++){
                int ncol = n0 + ni*16 + l16;
                size_t o = (size_t)brow*H_ + ncol;
                if(dosplit) pg[o] = acc[mi][ni][r];
                else        atomicAdd(&pg[o], acc[mi][ni][r]);
            }
        }
    }
}

// ---------------- combine: sum kc partials + f32 outputs ----------------
__global__ __launch_bounds__(256) void k_combine(const float* __restrict__ part,
    int nsplit, int climit,
    const void* __restrict__ c,
    const void* __restrict__ bi, const void* __restrict__ bfv,
    const void* __restrict__ bc, const void* __restrict__ bo,
    const int* __restrict__ flags,
    float* __restrict__ out){
    int b = blockIdx.x, t = threadIdx.x;
    int isf32 = flags[1];
    const size_t G = (size_t)B_*H_;
    for(int i=0;i<4;i++){
        int n = i*256 + t;
        size_t idx = (size_t)b*H_ + n;
        float pi = 0.f, pf = 0.f, pcv = 0.f, po = 0.f;
        for(int p=0;p<nsplit;p++){
            const float* pp = part + (size_t)p*4*G;
            pi += pp[idx];
            pf += pp[G + idx];
            po += pp[3*G + idx];
            if(p < climit) pcv += pp[2*G + idx];
        }
        pi  += loads(bi,  n, isf32);
        pf  += loads(bfv, n, isf32);
        pcv += loads(bc,  n, isf32);
        po  += loads(bo,  n, isf32);
        float ig = sigmoidf_(pi);
        float fg = sigmoidf_(pf);
        float og = sigmoidf_(po);
        float cold = loads(c, idx, isf32);
        float ncv = fg*cold + ig*fast_tanh(pcv);
        float nh  = og*fast_tanh(ncv);
        out[idx]     = nh;    // new_h
        out[G + idx] = ncv;   // new_c
    }
}

extern "C" void kernel_launch(void* const* d_in, const int* in_sizes, int n_in,
                              void* d_out, int out_size, void* d_ws, size_t ws_size,
                              hipStream_t stream){
    const void* xj   = d_in[0];
    const void* mask = d_in[1];
    const void* XF   = d_in[2];
    const void* h    = d_in[3];
    const void* c    = d_in[4];
    const void* Wi   = d_in[5];
    const void* Wf   = d_in[6];
    const void* Wc   = d_in[7];
    const void* Wo   = d_in[8];
    const void* Ui   = d_in[9];
    const void* Uf   = d_in[10];
    const void* Uc   = d_in[11];
    const void* Uo   = d_in[12];
    const void* Vi   = d_in[13];
    const void* Vf   = d_in[14];
    // d_in[15] = V_c : unused by the reference
    const void* Vo   = d_in[16];
    const void* bi   = d_in[17];
    const void* bfv  = d_in[18];
    const void* bc   = d_in[19];
    const void* bo   = d_in[20];
    const void* wv   = d_in[21];
    const void* We   = d_in[22];
    const void* Ue   = d_in[23];
    const void* be   = d_in[24];

    char* ws = (char*)d_ws;
    float* hwe  = (float*)(ws + HWE_OFF);
    u16*   Xc   = (u16*)(ws + XC_OFF);
    float* pre  = (float*)(ws + PRE_OFF);   // Epart during attention phase
    int*   flags= (int*)(ws + FLAG_OFF);
    float* out  = (float*)d_out;

    int big = (ws_size >= (size_t)WS_BIG);
    u16* ue16 = (u16*)(ws + UE16_OFF);
    float* gpart = (float*)(ws + GPART_OFF);   // xj16 region: now exclusively gpart
    const void* UeA = big ? (const void*)ue16 : Ue;

    k_detect<<<1, 256, 0, stream>>>((const u8*)mask, (const u16*)xj, flags);
    hipMemsetAsync(hwe, 0, (size_t)B_*Hh_*sizeof(float), stream);
    // pack (3584 blocks) + Ue bf16 conversion (256 blocks, big only)
    k_pack<<<3584 + (big ? 256 : 0), 256, 0, stream>>>(XF, h, c, Ue, flags, 3584, Xc, ue16);
    k_hwe<<<dim3(8,8,2), 256, 0, stream>>>(h, We, flags, hwe);
    k_attn<<<dim3(B_, 8), 256, 0, stream>>>(xj, wv, UeA, be, hwe, flags, big, pre);
    k_soft<<<B_, 512, 0, stream>>>(pre, mask, xj, flags, Xc);
    if(big){
        k_gates<<<dim3(64, 8), 512, 0, stream>>>(Xc, Wi,Wf,Wc,Wo, Ui,Uf,Uc,Uo, Vi,Vf,Vo, flags, 1, gpart);
        k_combine<<<B_, 256, 0, stream>>>(gpart, 8, 6, c, bi, bfv, bc, bo, flags, out);
    } else {
        hipMemsetAsync(pre, 0, (size_t)4*B_*H_*sizeof(float), stream);
        k_gates<<<dim3(64, 8), 512, 0, stream>>>(Xc, Wi,Wf,Wc,Wo, Ui,Uf,Uc,Uo, Vi,Vf,Vo, flags, 0, pre);
        k_combine<<<B_, 256, 0, stream>>>(pre, 1, 1, c, bi, bfv, bc, bo, flags, out);
    }
}

// Round 8
// 303.571 us; speedup vs baseline: 1.5464x; 1.0013x over previous
//
#include <hip/hip_runtime.h>
#include <hip/hip_bf16.h>

typedef unsigned char u8;
typedef unsigned short u16;
typedef unsigned int u32;
typedef __attribute__((ext_vector_type(8))) short bf8;
typedef __attribute__((ext_vector_type(4))) float f4;

#define B_ 256
#define O_ 128
#define Hh_ 512
#define H_ 1024
#define DF_ 1536
#define I_ 2048

// ws layout (bytes)
#define HWE_OFF   0          // 256*512 f32 = 524288
#define XC_OFF    524288     // 256*4096 bf16 = 2097152
#define PRE_OFF   2621440    // 4 MB: Epart (512 KB) during attn; atomic-fallback pre
#define FLAG_OFF  6815744    // ints
#define XJ16_OFF  7340032    // 32 MB region [big-ws only] — gpart
#define UE16_OFF  40894464   // 262144 bf16 = 524288       [big-ws only]
#define WS_BIG    41418752
#define GPART_OFF XJ16_OFF   // 8 kc * 4 gates * 256*1024 f32 = 33554432

__device__ __forceinline__ float bf1(u16 u){ union{u32 i; float f;} v; v.i = ((u32)u)<<16; return v.f; }
__device__ __forceinline__ u16 f2bf(float f){
    __hip_bfloat16 h = __float2bfloat16(f);
    union{ __hip_bfloat16 h; u16 u; } v; v.h = h; return v.u;
}
__device__ __forceinline__ u32 pack2(float a, float b){
    return ((u32)f2bf(a)) | (((u32)f2bf(b))<<16);
}
struct P8 { uint4 lo, hi; };
__device__ __forceinline__ P8 fetch8(const void* p, size_t idx, int isf32){
    P8 r;
    if(isf32){
        const uint4* f = (const uint4*)((const float*)p + idx);
        r.lo = f[0]; r.hi = f[1];
    } else {
        r.lo = *(const uint4*)((const u16*)p + idx);
    }
    return r;
}
__device__ __forceinline__ uint4 cvt8(P8 r, int isf32){
    if(isf32){
        float4 x = *(float4*)&r.lo, y = *(float4*)&r.hi;
        uint4 o;
        o.x = pack2(x.x,x.y); o.y = pack2(x.z,x.w);
        o.z = pack2(y.x,y.y); o.w = pack2(y.z,y.w);
        return o;
    }
    return r.lo;
}
__device__ __forceinline__ uint4 load8(const void* p, size_t idx, int isf32){
    return cvt8(fetch8(p, idx, isf32), isf32);
}
__device__ __forceinline__ float loads(const void* p, size_t idx, int isf32){
    return isf32 ? ((const float*)p)[idx] : bf1(((const u16*)p)[idx]);
}
__device__ __forceinline__ float fast_tanh(float x){
    return 1.0f - 2.0f/(__expf(2.0f*x)+1.0f);
}
__device__ __forceinline__ float sigmoidf_(float x){
    return 1.0f/(1.0f+__expf(-x));
}

// ---------------- dtype detection ----------------
__global__ void k_detect(const u8* __restrict__ m, const u16* __restrict__ xj,
                         int* __restrict__ flags){
    __shared__ int n1, n2, n3, mb, xo;
    int t = threadIdx.x;
    if(t==0){ n1=0; n2=0; n3=0; mb=0; xo=0; }
    __syncthreads();
    int a1=0, a2=0, a3=0, amax=0;
    for(int i=t; i<8192; i+=256){
        int v = m[i]; int c = i&3;
        if(c==1) a1|=v;
        if(c==2) a2|=v;
        if(c==3) a3|=v;
        amax = amax > v ? amax : v;
    }
    if(a1) atomicOr(&n1,1);
    if(a2) atomicOr(&n2,1);
    if(a3) atomicOr(&n3,1);
    atomicMax(&mb, amax);
    int e = 0;
    for(int i=t; i<2048; i+=256){
        u32 u = xj[2*i];
        int ex = (u>>7)&0xFF;
        if(ex >= 156) e = 1;
    }
    if(e) atomicOr(&xo,1);
    __syncthreads();
    if(t==0){
        int w;
        if(!n1 && !n2 && !n3)      w = 4;   // int32
        else if(!n1 && n2 && n3)   w = 4;   // f32
        else if(mb > 1)            w = 2;   // bf16
        else                       w = 1;   // bool8
        flags[0] = w;
        flags[1] = xo;
    }
}

// ---------------- pack X_F | h | c into Xc[512:4096) + Ue->ue16 conversion ----------------
__global__ __launch_bounds__(256) void k_pack(const void* __restrict__ XF,
                                              const void* __restrict__ h,
                                              const void* __restrict__ c,
                                              const void* __restrict__ Ue,
                                              const int* __restrict__ flags,
                                              int packN,
                                              u16* __restrict__ Xc,
                                              u16* __restrict__ ue16){
    int bid = blockIdx.x, t = threadIdx.x;
    int isf32 = flags[1];
    if(bid < packN){
        int b = bid/14;
        int r = (bid%14)*256 + t;   // 0..3583
        float v;
        if(r < DF_)            v = loads(XF, (size_t)b*DF_ + r, isf32);
        else if(r < DF_ + H_)  v = loads(h,  (size_t)b*H_ + (r - DF_), isf32);
        else                   v = loads(c,  (size_t)b*H_ + (r - DF_ - H_), isf32);
        Xc[(size_t)b*4096 + 512 + r] = f2bf(v);
    } else {
        size_t g = (size_t)(bid - packN)*256 + t;   // 0..65535
        size_t idx = g*8;                            // 524288 elems
        *(uint4*)&ue16[idx] = load8(Ue, idx, isf32);
    }
}

// ---------------- hwe GEMM, K-split: grid (8 n, 8 kc, 2 m), 256 thr, atomics ----------------
__global__ __launch_bounds__(256) void k_hwe(const void* __restrict__ h,
                                             const void* __restrict__ We,
                                             const int* __restrict__ flags,
                                             float* __restrict__ hwe){
    int n0 = blockIdx.x*64;
    int kc = blockIdx.y*128;
    int m0 = blockIdx.z*128;
    int t = threadIdx.x;
    int isf32 = flags[1];
    __shared__ __align__(16) u16 As[128*40];
    __shared__ __align__(16) u16 Bs[64*40];
    int w = t>>6, lane = t&63;
    int q = lane>>4, l16 = lane&15;
    int koff = q*8;
    f4 acc[2][4];
    for(int mi=0;mi<2;mi++) for(int ni=0;ni<4;ni++){
        f4 z = {0.f,0.f,0.f,0.f}; acc[mi][ni] = z;
    }
    for(int ks=0; ks<128; ks+=32){
        __syncthreads();
        for(int i=0;i<2;i++){
            int row = i*64 + (t>>2), cv = t&3;
            uint4 va = load8(h, (size_t)(m0+row)*H_ + kc + ks + cv*8, isf32);
            *(uint4*)&As[row*40 + cv*8] = va;
        }
        {
            int row = t>>2, cv = t&3;
            uint4 vb = load8(We, (size_t)(n0+row)*H_ + kc + ks + cv*8, isf32);
            *(uint4*)&Bs[row*40 + cv*8] = vb;
        }
        __syncthreads();
        bf8 af[2], bfr[4];
        for(int mi=0;mi<2;mi++) af[mi]  = *(const bf8*)&As[(w*32+mi*16+l16)*40 + koff];
        for(int ni=0;ni<4;ni++) bfr[ni] = *(const bf8*)&Bs[(ni*16+l16)*40 + koff];
        for(int mi=0;mi<2;mi++)
            for(int ni=0;ni<4;ni++)
                acc[mi][ni] = __builtin_amdgcn_mfma_f32_16x16x32_bf16(af[mi], bfr[ni], acc[mi][ni], 0,0,0);
    }
    for(int mi=0;mi<2;mi++){
        for(int r=0;r<4;r++){
            int brow = m0 + w*32 + mi*16 + q*4 + r;
            for(int ni=0;ni<4;ni++){
                int ncol = n0 + ni*16 + l16;
                atomicAdd(&hwe[(size_t)brow*Hh_ + ncol], acc[mi][ni][r]);
            }
        }
    }
}

// ---------------- attention e-score GEMM: grid (256 b, 4 n-tiles of 128), 256 thr ----------------
// A (xj) read RAW f32/bf16 and converted during staging — staged once per block,
// amortized over 128 n-cols (halves the A-duplication vs 8x64 blocks).
__global__ __launch_bounds__(256) void k_attn(const void* __restrict__ xjA,
                                              const void* __restrict__ wvec,
                                              const void* __restrict__ UeA,
                                              const void* __restrict__ be,
                                              const float* __restrict__ hwe,
                                              const int* __restrict__ flags,
                                              int srcbfB,
                                              float* __restrict__ Epart){
    int b = blockIdx.x, y = blockIdx.y, t = threadIdx.x;
    int isf = flags[1];               // for be/wvec/xjA (original inputs)
    int isA = isf;                    // xj is always the raw input
    int isB = srcbfB ? 0 : isf;       // UeA (bf16 master when big-ws)
    __shared__ __align__(16) u16 As[128*40];
    __shared__ __align__(16) u16 Bs[128*40];
    __shared__ float hwes[128];
    __shared__ float wvs[128];

    if(t < 128){
        int col = y*128 + t;
        hwes[t] = hwe[(size_t)b*Hh_ + col] + loads(be, col, isf);
        wvs[t]  = loads(wvec, col, isf);
    }

    const size_t xboff = (size_t)b*O_*Hh_;
    int w = t>>6, lane = t&63;
    int q = lane>>4, l16 = lane&15;
    int koff = q*8;
    int rA = t>>2, cA = t&3;          // A rows rA, rA+64; B rows rA, rA+64

    f4 acc[2][8];
    for(int mi=0;mi<2;mi++) for(int ni=0;ni<8;ni++){
        f4 z = {0.f,0.f,0.f,0.f}; acc[mi][ni] = z;
    }

    P8 pa0, pa1, pb0, pb1;
    pa0 = fetch8(xjA, xboff + (size_t)rA*Hh_      + cA*8, isA);
    pa1 = fetch8(xjA, xboff + (size_t)(rA+64)*Hh_ + cA*8, isA);
    pb0 = fetch8(UeA, (size_t)(y*128 + rA)*Hh_      + cA*8, isB);
    pb1 = fetch8(UeA, (size_t)(y*128 + rA + 64)*Hh_ + cA*8, isB);

    for(int ks=0; ks<Hh_; ks+=32){
        __syncthreads();
        *(uint4*)&As[rA*40 + cA*8]      = cvt8(pa0, isA);
        *(uint4*)&As[(rA+64)*40 + cA*8] = cvt8(pa1, isA);
        *(uint4*)&Bs[rA*40 + cA*8]      = cvt8(pb0, isB);
        *(uint4*)&Bs[(rA+64)*40 + cA*8] = cvt8(pb1, isB);
        __syncthreads();
        if(ks + 32 < Hh_){
            int kn = ks + 32;
            pa0 = fetch8(xjA, xboff + (size_t)rA*Hh_      + kn + cA*8, isA);
            pa1 = fetch8(xjA, xboff + (size_t)(rA+64)*Hh_ + kn + cA*8, isA);
            pb0 = fetch8(UeA, (size_t)(y*128 + rA)*Hh_      + kn + cA*8, isB);
            pb1 = fetch8(UeA, (size_t)(y*128 + rA + 64)*Hh_ + kn + cA*8, isB);
        }
        bf8 af[2], bfr[8];
        for(int mi=0;mi<2;mi++) af[mi]  = *(const bf8*)&As[(w*32+mi*16+l16)*40 + koff];
        for(int ni=0;ni<8;ni++) bfr[ni] = *(const bf8*)&Bs[(ni*16+l16)*40 + koff];
        for(int mi=0;mi<2;mi++)
            for(int ni=0;ni<8;ni++)
                acc[mi][ni] = __builtin_amdgcn_mfma_f32_16x16x32_bf16(af[mi], bfr[ni], acc[mi][ni], 0,0,0);
    }
    // epilogue: each wave owns disjoint o-rows -> plain stores, no atomics
    for(int mi=0;mi<2;mi++){
        for(int r=0;r<4;r++){
            int o = w*32 + mi*16 + q*4 + r;
            float part = 0.f;
            for(int ni=0;ni<8;ni++){
                int col = ni*16 + l16;
                part += wvs[col] * fast_tanh(hwes[col] + acc[mi][ni][r]);
            }
            part += __shfl_xor(part, 1);
            part += __shfl_xor(part, 2);
            part += __shfl_xor(part, 4);
            part += __shfl_xor(part, 8);
            if(l16 == 0) Epart[(size_t)y*32768 + (size_t)b*O_ + o] = part;
        }
    }
}

// ---------------- softmax + phi: grid 256 (per b), 512 thr ----------------
__global__ __launch_bounds__(512) void k_soft(const float* __restrict__ Epart,
                                              const void* __restrict__ maskp,
                                              const void* __restrict__ xjA,
                                              const int* __restrict__ flags,
                                              u16* __restrict__ Xc){
    int b = blockIdx.x, t = threadIdx.x;
    int isf = flags[1];
    int isA = isf;                    // xj is always the raw input
    int mw = flags[0];
    __shared__ float es[O_];
    __shared__ float as_[O_];
    __shared__ float red[2];
    if(t < O_){
        float e = 0.f;
        for(int p=0;p<4;p++) e += Epart[(size_t)p*32768 + (size_t)b*O_ + t];
        size_t mi_ = (size_t)b*O_ + t;
        bool valid;
        if(mw == 1)      valid = ((const u8*)maskp)[mi_]  != 0;
        else if(mw == 2) valid = ((const u16*)maskp)[mi_] != 0;
        else             valid = ((const u32*)maskp)[mi_] != 0;
        es[t] = valid ? e : -1e30f;
    }
    __syncthreads();
    if(t < 64){
        float v = fmaxf(es[t], es[t+64]);
        for(int m=32;m>0;m>>=1) v = fmaxf(v, __shfl_xor(v, m));
        if(t==0) red[0] = v;
    }
    __syncthreads();
    if(t < O_) as_[t] = __expf(es[t] - red[0]);
    __syncthreads();
    if(t < 64){
        float v = as_[t] + as_[t+64];
        for(int m=32;m>0;m>>=1) v += __shfl_xor(v, m);
        if(t==0) red[1] = v;
    }
    __syncthreads();
    float inv = 1.0f / red[1];
    float acc = 0.f;
    size_t base = (size_t)b*O_*Hh_ + t;
    #pragma unroll 8
    for(int o=0;o<O_;o++){
        acc += as_[o] * loads(xjA, base + (size_t)o*Hh_, isA);
    }
    Xc[(size_t)b*4096 + t] = f2bf(acc * inv);
}

// ---------------- gates GEMM, K-split: grid (64 nt, 8 kc of 512), 512 thr, BK=32 ----------------
__global__ __launch_bounds__(512) void k_gates(const u16* __restrict__ Xc,
    const void* __restrict__ Wi, const void* __restrict__ Wf, const void* __restrict__ Wc, const void* __restrict__ Wo,
    const void* __restrict__ Ui, const void* __restrict__ Uf, const void* __restrict__ Uc, const void* __restrict__ Uo,
    const void* __restrict__ Vi, const void* __restrict__ Vf, const void* __restrict__ Vo,
    const int* __restrict__ flags,
    int dosplit,
    float* __restrict__ part){
    int nt = blockIdx.x;          // gate g = nt>>4, n-tile nt&15
    int kc = blockIdx.y;          // K-chunk of 512
    int g  = nt>>4;
    int k0 = kc*512;
    if(g == 2 && k0 >= 3072) return; // c-gate has no V peephole
    int isf32 = flags[1];
    const void* Wm = (g==0)?Wi:(g==1)?Wf:(g==2)?Wc:Wo;
    const void* Um = (g==0)?Ui:(g==1)?Uf:(g==2)?Uc:Uo;
    const void* Vm = (g==0)?Vi:(g==1)?Vf:(g==3)?Vo:Vi;  // g==2 never dereferences V
    int n0 = (nt&15)*64;
    int t = threadIdx.x;
    __shared__ __align__(16) u16 As[256*40];
    __shared__ __align__(16) u16 Bs[64*40];
    int w = t>>6, lane = t&63;
    int q = lane>>4, l16 = lane&15;
    int koff = q*8;
    int rA = t>>2, cA = t&3;      // A rows rA, rA+128 (rA 0..127); B row rA if t<256
    bool hasB = (t < 256);

    f4 acc[2][4];
    for(int mi=0;mi<2;mi++) for(int ni=0;ni<4;ni++){
        f4 z = {0.f,0.f,0.f,0.f}; acc[mi][ni] = z;
    }

    auto fetchB = [&](int k)->P8{
        int n = n0 + rA;
        if(k < 2048)       return fetch8(Wm, (size_t)n*I_ + k, isf32);
        else if(k < 3072)  return fetch8(Um, (size_t)n*H_ + (k-2048), isf32);
        else               return fetch8(Vm, (size_t)n*H_ + (k-3072), isf32);
    };

    uint4 qa0, qa1; P8 qb;
    qa0 = *(const uint4*)(Xc + (size_t)rA*4096       + k0 + cA*8);
    qa1 = *(const uint4*)(Xc + (size_t)(rA+128)*4096 + k0 + cA*8);
    if(hasB) qb = fetchB(k0 + cA*8);

    for(int ks=0; ks<512; ks+=32){
        __syncthreads();
        *(uint4*)&As[rA*40 + cA*8]       = qa0;
        *(uint4*)&As[(rA+128)*40 + cA*8] = qa1;
        if(hasB) *(uint4*)&Bs[rA*40 + cA*8] = cvt8(qb, isf32);
        __syncthreads();
        if(ks + 32 < 512){
            int kn = k0 + ks + 32;
            qa0 = *(const uint4*)(Xc + (size_t)rA*4096       + kn + cA*8);
            qa1 = *(const uint4*)(Xc + (size_t)(rA+128)*4096 + kn + cA*8);
            if(hasB) qb = fetchB(kn + cA*8);
        }
        bf8 af[2], bfr[4];
        for(int mi=0;mi<2;mi++) af[mi]  = *(const bf8*)&As[(w*32+mi*16+l16)*40 + koff];
        for(int ni=0;ni<4;ni++) bfr[ni] = *(const bf8*)&Bs[(ni*16+l16)*40 + koff];
        for(int mi=0;mi<2;mi++)
            for(int ni=0;ni<4;ni++)
                acc[mi][ni] = __builtin_amdgcn_mfma_f32_16x16x32_bf16(af[mi], bfr[ni], acc[mi][ni], 0,0,0);
    }
    float* pg = dosplit ? (part + ((size_t)kc*4 + g)*(size_t)(B_*H_))
                        : (part + (size_t)g*(B_*H_));
    for(int mi=0;mi<2;mi++){
        for(int r=0;r<4;r++){
            int brow = w*32 + mi*16 + q*4 + r;
            for(int ni=0;ni<4;ni++){
                int ncol = n0 + ni*16 + l16;
                size_t o = (size_t)brow*H_ + ncol;
                if(dosplit) pg[o] = acc[mi][ni][r];
                else        atomicAdd(&pg[o], acc[mi][ni][r]);
            }
        }
    }
}

// ---------------- combine: sum kc partials + f32 outputs ----------------
__global__ __launch_bounds__(256) void k_combine(const float* __restrict__ part,
    int nsplit, int climit,
    const void* __restrict__ c,
    const void* __restrict__ bi, const void* __restrict__ bfv,
    const void* __restrict__ bc, const void* __restrict__ bo,
    const int* __restrict__ flags,
    float* __restrict__ out){
    int b = blockIdx.x, t = threadIdx.x;
    int isf32 = flags[1];
    const size_t G = (size_t)B_*H_;
    for(int i=0;i<4;i++){
        int n = i*256 + t;
        size_t idx = (size_t)b*H_ + n;
        float pi = 0.f, pf = 0.f, pcv = 0.f, po = 0.f;
        for(int p=0;p<nsplit;p++){
            const float* pp = part + (size_t)p*4*G;
            pi += pp[idx];
            pf += pp[G + idx];
            po += pp[3*G + idx];
            if(p < climit) pcv += pp[2*G + idx];
        }
        pi  += loads(bi,  n, isf32);
        pf  += loads(bfv, n, isf32);
        pcv += loads(bc,  n, isf32);
        po  += loads(bo,  n, isf32);
        float ig = sigmoidf_(pi);
        float fg = sigmoidf_(pf);
        float og = sigmoidf_(po);
        float cold = loads(c, idx, isf32);
        float ncv = fg*cold + ig*fast_tanh(pcv);
        float nh  = og*fast_tanh(ncv);
        out[idx]     = nh;    // new_h
        out[G + idx] = ncv;   // new_c
    }
}

extern "C" void kernel_launch(void* const* d_in, const int* in_sizes, int n_in,
                              void* d_out, int out_size, void* d_ws, size_t ws_size,
                              hipStream_t stream){
    const void* xj   = d_in[0];
    const void* mask = d_in[1];
    const void* XF   = d_in[2];
    const void* h    = d_in[3];
    const void* c    = d_in[4];
    const void* Wi   = d_in[5];
    const void* Wf   = d_in[6];
    const void* Wc   = d_in[7];
    const void* Wo   = d_in[8];
    const void* Ui   = d_in[9];
    const void* Uf   = d_in[10];
    const void* Uc   = d_in[11];
    const void* Uo   = d_in[12];
    const void* Vi   = d_in[13];
    const void* Vf   = d_in[14];
    // d_in[15] = V_c : unused by the reference
    const void* Vo   = d_in[16];
    const void* bi   = d_in[17];
    const void* bfv  = d_in[18];
    const void* bc   = d_in[19];
    const void* bo   = d_in[20];
    const void* wv   = d_in[21];
    const void* We   = d_in[22];
    const void* Ue   = d_in[23];
    const void* be   = d_in[24];

    char* ws = (char*)d_ws;
    float* hwe  = (float*)(ws + HWE_OFF);
    u16*   Xc   = (u16*)(ws + XC_OFF);
    float* pre  = (float*)(ws + PRE_OFF);   // Epart during attention phase
    int*   flags= (int*)(ws + FLAG_OFF);
    float* out  = (float*)d_out;

    int big = (ws_size >= (size_t)WS_BIG);
    u16* ue16 = (u16*)(ws + UE16_OFF);
    float* gpart = (float*)(ws + GPART_OFF);
    const void* UeA = big ? (const void*)ue16 : Ue;

    k_detect<<<1, 256, 0, stream>>>((const u8*)mask, (const u16*)xj, flags);
    hipMemsetAsync(hwe, 0, (size_t)B_*Hh_*sizeof(float), stream);
    // pack (3584 blocks) + Ue bf16 conversion (256 blocks, big only)
    k_pack<<<3584 + (big ? 256 : 0), 256, 0, stream>>>(XF, h, c, Ue, flags, 3584, Xc, ue16);
    k_hwe<<<dim3(8,8,2), 256, 0, stream>>>(h, We, flags, hwe);
    k_attn<<<dim3(B_, 4), 256, 0, stream>>>(xj, wv, UeA, be, hwe, flags, big, pre);
    k_soft<<<B_, 512, 0, stream>>>(pre, mask, xj, flags, Xc);
    if(big){
        k_gates<<<dim3(64, 8), 512, 0, stream>>>(Xc, Wi,Wf,Wc,Wo, Ui,Uf,Uc,Uo, Vi,Vf,Vo, flags, 1, gpart);
        k_combine<<<B_, 256, 0, stream>>>(gpart, 8, 6, c, bi, bfv, bc, bo, flags, out);
    } else {
        hipMemsetAsync(pre, 0, (size_t)4*B_*H_*sizeof(float), stream);
        k_gates<<<dim3(64, 8), 512, 0, stream>>>(Xc, Wi,Wf,Wc,Wo, Ui,Uf,Uc,Uo, Vi,Vf,Vo, flags, 0, pre);
        k_combine<<<B_, 256, 0, stream>>>(pre, 1, 1, c, bi, bfv, bc, bo, flags, out);
    }
}

// Round 9
// 297.670 us; speedup vs baseline: 1.5770x; 1.0198x over previous
//
#include <hip/hip_runtime.h>
#include <hip/hip_bf16.h>

typedef unsigned char u8;
typedef unsigned short u16;
typedef unsigned int u32;
typedef __attribute__((ext_vector_type(8))) short bf8;
typedef __attribute__((ext_vector_type(4))) float f4;

#define B_ 256
#define O_ 128
#define Hh_ 512
#define H_ 1024
#define DF_ 1536
#define I_ 2048

// ws layout (bytes)
#define HWE_OFF   0          // 256*512 f32 = 524288
#define XC_OFF    524288     // 256*4096 bf16 = 2097152
#define PRE_OFF   2621440    // 4 MB: Epart (512 KB) during attn; atomic-fallback pre
#define FLAG_OFF  6815744    // ints
#define XJ16_OFF  7340032    // 32 MB region [big-ws only] — gpart
#define UE16_OFF  40894464   // 262144 bf16 = 524288       [big-ws only]
#define WS_BIG    41418752
#define GPART_OFF XJ16_OFF   // 8 kc * 4 gates * 256*1024 f32 = 33554432

__device__ __forceinline__ float bf1(u16 u){ union{u32 i; float f;} v; v.i = ((u32)u)<<16; return v.f; }
__device__ __forceinline__ u16 f2bf(float f){
    __hip_bfloat16 h = __float2bfloat16(f);
    union{ __hip_bfloat16 h; u16 u; } v; v.h = h; return v.u;
}
__device__ __forceinline__ u32 pack2(float a, float b){
    return ((u32)f2bf(a)) | (((u32)f2bf(b))<<16);
}
struct P8 { uint4 lo, hi; };
__device__ __forceinline__ P8 fetch8(const void* p, size_t idx, int isf32){
    P8 r;
    if(isf32){
        const uint4* f = (const uint4*)((const float*)p + idx);
        r.lo = f[0]; r.hi = f[1];
    } else {
        r.lo = *(const uint4*)((const u16*)p + idx);
    }
    return r;
}
__device__ __forceinline__ uint4 cvt8(P8 r, int isf32){
    if(isf32){
        float4 x = *(float4*)&r.lo, y = *(float4*)&r.hi;
        uint4 o;
        o.x = pack2(x.x,x.y); o.y = pack2(x.z,x.w);
        o.z = pack2(y.x,y.y); o.w = pack2(y.z,y.w);
        return o;
    }
    return r.lo;
}
__device__ __forceinline__ uint4 load8(const void* p, size_t idx, int isf32){
    return cvt8(fetch8(p, idx, isf32), isf32);
}
__device__ __forceinline__ float loads(const void* p, size_t idx, int isf32){
    return isf32 ? ((const float*)p)[idx] : bf1(((const u16*)p)[idx]);
}
__device__ __forceinline__ float fast_tanh(float x){
    return 1.0f - 2.0f/(__expf(2.0f*x)+1.0f);
}
__device__ __forceinline__ float sigmoidf_(float x){
    return 1.0f/(1.0f+__expf(-x));
}

// ---------------- dtype detection ----------------
__global__ void k_detect(const u8* __restrict__ m, const u16* __restrict__ xj,
                         int* __restrict__ flags){
    __shared__ int n1, n2, n3, mb, xo;
    int t = threadIdx.x;
    if(t==0){ n1=0; n2=0; n3=0; mb=0; xo=0; }
    __syncthreads();
    int a1=0, a2=0, a3=0, amax=0;
    for(int i=t; i<8192; i+=256){
        int v = m[i]; int c = i&3;
        if(c==1) a1|=v;
        if(c==2) a2|=v;
        if(c==3) a3|=v;
        amax = amax > v ? amax : v;
    }
    if(a1) atomicOr(&n1,1);
    if(a2) atomicOr(&n2,1);
    if(a3) atomicOr(&n3,1);
    atomicMax(&mb, amax);
    int e = 0;
    for(int i=t; i<2048; i+=256){
        u32 u = xj[2*i];
        int ex = (u>>7)&0xFF;
        if(ex >= 156) e = 1;
    }
    if(e) atomicOr(&xo,1);
    __syncthreads();
    if(t==0){
        int w;
        if(!n1 && !n2 && !n3)      w = 4;   // int32
        else if(!n1 && n2 && n3)   w = 4;   // f32
        else if(mb > 1)            w = 2;   // bf16
        else                       w = 1;   // bool8
        flags[0] = w;
        flags[1] = xo;
    }
}

// ---------------- pack X_F | h | c into Xc[512:4096) + Ue->ue16 conversion ----------------
__global__ __launch_bounds__(256) void k_pack(const void* __restrict__ XF,
                                              const void* __restrict__ h,
                                              const void* __restrict__ c,
                                              const void* __restrict__ Ue,
                                              const int* __restrict__ flags,
                                              int packN,
                                              u16* __restrict__ Xc,
                                              u16* __restrict__ ue16){
    int bid = blockIdx.x, t = threadIdx.x;
    int isf32 = flags[1];
    if(bid < packN){
        int b = bid/14;
        int r = (bid%14)*256 + t;   // 0..3583
        float v;
        if(r < DF_)            v = loads(XF, (size_t)b*DF_ + r, isf32);
        else if(r < DF_ + H_)  v = loads(h,  (size_t)b*H_ + (r - DF_), isf32);
        else                   v = loads(c,  (size_t)b*H_ + (r - DF_ - H_), isf32);
        Xc[(size_t)b*4096 + 512 + r] = f2bf(v);
    } else {
        size_t g = (size_t)(bid - packN)*256 + t;   // 0..65535
        size_t idx = g*8;                            // 524288 elems
        *(uint4*)&ue16[idx] = load8(Ue, idx, isf32);
    }
}

// ---------------- hwe GEMM, K-split: grid (8 n, 8 kc, 2 m), 256 thr, atomics ----------------
__global__ __launch_bounds__(256) void k_hwe(const void* __restrict__ h,
                                             const void* __restrict__ We,
                                             const int* __restrict__ flags,
                                             float* __restrict__ hwe){
    int n0 = blockIdx.x*64;
    int kc = blockIdx.y*128;
    int m0 = blockIdx.z*128;
    int t = threadIdx.x;
    int isf32 = flags[1];
    __shared__ __align__(16) u16 As[128*40];
    __shared__ __align__(16) u16 Bs[64*40];
    int w = t>>6, lane = t&63;
    int q = lane>>4, l16 = lane&15;
    int koff = q*8;
    f4 acc[2][4];
    for(int mi=0;mi<2;mi++) for(int ni=0;ni<4;ni++){
        f4 z = {0.f,0.f,0.f,0.f}; acc[mi][ni] = z;
    }
    for(int ks=0; ks<128; ks+=32){
        __syncthreads();
        for(int i=0;i<2;i++){
            int row = i*64 + (t>>2), cv = t&3;
            uint4 va = load8(h, (size_t)(m0+row)*H_ + kc + ks + cv*8, isf32);
            *(uint4*)&As[row*40 + cv*8] = va;
        }
        {
            int row = t>>2, cv = t&3;
            uint4 vb = load8(We, (size_t)(n0+row)*H_ + kc + ks + cv*8, isf32);
            *(uint4*)&Bs[row*40 + cv*8] = vb;
        }
        __syncthreads();
        bf8 af[2], bfr[4];
        for(int mi=0;mi<2;mi++) af[mi]  = *(const bf8*)&As[(w*32+mi*16+l16)*40 + koff];
        for(int ni=0;ni<4;ni++) bfr[ni] = *(const bf8*)&Bs[(ni*16+l16)*40 + koff];
        for(int mi=0;mi<2;mi++)
            for(int ni=0;ni<4;ni++)
                acc[mi][ni] = __builtin_amdgcn_mfma_f32_16x16x32_bf16(af[mi], bfr[ni], acc[mi][ni], 0,0,0);
    }
    for(int mi=0;mi<2;mi++){
        for(int r=0;r<4;r++){
            int brow = m0 + w*32 + mi*16 + q*4 + r;
            for(int ni=0;ni<4;ni++){
                int ncol = n0 + ni*16 + l16;
                atomicAdd(&hwe[(size_t)brow*Hh_ + ncol], acc[mi][ni][r]);
            }
        }
    }
}

// ---------------- attention e-score GEMM: grid (256 b, 4 n-tiles of 128), 512 thr ----------------
// 8 waves/block: wave w owns 16 o-rows. Same 128x128 tile and staging volume as R8,
// but 2x the waves for latency hiding; acc shrinks to 8 f4/thread, prefetch to 1+1 P8.
__global__ __launch_bounds__(512) void k_attn(const void* __restrict__ xjA,
                                              const void* __restrict__ wvec,
                                              const void* __restrict__ UeA,
                                              const void* __restrict__ be,
                                              const float* __restrict__ hwe,
                                              const int* __restrict__ flags,
                                              int srcbfB,
                                              float* __restrict__ Epart){
    int b = blockIdx.x, y = blockIdx.y, t = threadIdx.x;
    int isf = flags[1];               // for be/wvec/xjA (original inputs)
    int isA = isf;                    // xj is always the raw input
    int isB = srcbfB ? 0 : isf;       // UeA (bf16 master when big-ws)
    __shared__ __align__(16) u16 As[128*40];
    __shared__ __align__(16) u16 Bs[128*40];
    __shared__ float hwes[128];
    __shared__ float wvs[128];

    if(t < 128){
        int col = y*128 + t;
        hwes[t] = hwe[(size_t)b*Hh_ + col] + loads(be, col, isf);
        wvs[t]  = loads(wvec, col, isf);
    }

    const size_t xboff = (size_t)b*O_*Hh_;
    int w = t>>6, lane = t&63;
    int q = lane>>4, l16 = lane&15;
    int koff = q*8;
    int rA = t>>2, cA = t&3;          // staging: row rA (0..127), chunk cA — 1 uint4/thread each

    f4 acc[8];
    for(int ni=0;ni<8;ni++){
        f4 z = {0.f,0.f,0.f,0.f}; acc[ni] = z;
    }

    P8 pa, pb;
    pa = fetch8(xjA, xboff + (size_t)rA*Hh_        + cA*8, isA);
    pb = fetch8(UeA, (size_t)(y*128 + rA)*Hh_      + cA*8, isB);

    for(int ks=0; ks<Hh_; ks+=32){
        __syncthreads();
        *(uint4*)&As[rA*40 + cA*8] = cvt8(pa, isA);
        *(uint4*)&Bs[rA*40 + cA*8] = cvt8(pb, isB);
        __syncthreads();
        if(ks + 32 < Hh_){
            int kn = ks + 32;
            pa = fetch8(xjA, xboff + (size_t)rA*Hh_        + kn + cA*8, isA);
            pb = fetch8(UeA, (size_t)(y*128 + rA)*Hh_      + kn + cA*8, isB);
        }
        bf8 af, bfr[8];
        af = *(const bf8*)&As[(w*16+l16)*40 + koff];
        for(int ni=0;ni<8;ni++) bfr[ni] = *(const bf8*)&Bs[(ni*16+l16)*40 + koff];
        for(int ni=0;ni<8;ni++)
            acc[ni] = __builtin_amdgcn_mfma_f32_16x16x32_bf16(af, bfr[ni], acc[ni], 0,0,0);
    }
    // epilogue: wave w owns o-rows w*16..w*16+15 -> plain stores, no atomics
    for(int r=0;r<4;r++){
        int o = w*16 + q*4 + r;
        float part = 0.f;
        for(int ni=0;ni<8;ni++){
            int col = ni*16 + l16;
            part += wvs[col] * fast_tanh(hwes[col] + acc[ni][r]);
        }
        part += __shfl_xor(part, 1);
        part += __shfl_xor(part, 2);
        part += __shfl_xor(part, 4);
        part += __shfl_xor(part, 8);
        if(l16 == 0) Epart[(size_t)y*32768 + (size_t)b*O_ + o] = part;
    }
}

// ---------------- softmax + phi: grid 256 (per b), 512 thr ----------------
__global__ __launch_bounds__(512) void k_soft(const float* __restrict__ Epart,
                                              const void* __restrict__ maskp,
                                              const void* __restrict__ xjA,
                                              const int* __restrict__ flags,
                                              u16* __restrict__ Xc){
    int b = blockIdx.x, t = threadIdx.x;
    int isf = flags[1];
    int isA = isf;                    // xj is always the raw input
    int mw = flags[0];
    __shared__ float es[O_];
    __shared__ float as_[O_];
    __shared__ float red[2];
    if(t < O_){
        float e = 0.f;
        for(int p=0;p<4;p++) e += Epart[(size_t)p*32768 + (size_t)b*O_ + t];
        size_t mi_ = (size_t)b*O_ + t;
        bool valid;
        if(mw == 1)      valid = ((const u8*)maskp)[mi_]  != 0;
        else if(mw == 2) valid = ((const u16*)maskp)[mi_] != 0;
        else             valid = ((const u32*)maskp)[mi_] != 0;
        es[t] = valid ? e : -1e30f;
    }
    __syncthreads();
    if(t < 64){
        float v = fmaxf(es[t], es[t+64]);
        for(int m=32;m>0;m>>=1) v = fmaxf(v, __shfl_xor(v, m));
        if(t==0) red[0] = v;
    }
    __syncthreads();
    if(t < O_) as_[t] = __expf(es[t] - red[0]);
    __syncthreads();
    if(t < 64){
        float v = as_[t] + as_[t+64];
        for(int m=32;m>0;m>>=1) v += __shfl_xor(v, m);
        if(t==0) red[1] = v;
    }
    __syncthreads();
    float inv = 1.0f / red[1];
    float acc = 0.f;
    size_t base = (size_t)b*O_*Hh_ + t;
    #pragma unroll 8
    for(int o=0;o<O_;o++){
        acc += as_[o] * loads(xjA, base + (size_t)o*Hh_, isA);
    }
    Xc[(size_t)b*4096 + t] = f2bf(acc * inv);
}

// ---------------- gates GEMM, K-split: grid (64 nt, 8 kc of 512), 512 thr, BK=32 ----------------
__global__ __launch_bounds__(512) void k_gates(const u16* __restrict__ Xc,
    const void* __restrict__ Wi, const void* __restrict__ Wf, const void* __restrict__ Wc, const void* __restrict__ Wo,
    const void* __restrict__ Ui, const void* __restrict__ Uf, const void* __restrict__ Uc, const void* __restrict__ Uo,
    const void* __restrict__ Vi, const void* __restrict__ Vf, const void* __restrict__ Vo,
    const int* __restrict__ flags,
    int dosplit,
    float* __restrict__ part){
    int nt = blockIdx.x;          // gate g = nt>>4, n-tile nt&15
    int kc = blockIdx.y;          // K-chunk of 512
    int g  = nt>>4;
    int k0 = kc*512;
    if(g == 2 && k0 >= 3072) return; // c-gate has no V peephole
    int isf32 = flags[1];
    const void* Wm = (g==0)?Wi:(g==1)?Wf:(g==2)?Wc:Wo;
    const void* Um = (g==0)?Ui:(g==1)?Uf:(g==2)?Uc:Uo;
    const void* Vm = (g==0)?Vi:(g==1)?Vf:(g==3)?Vo:Vi;  // g==2 never dereferences V
    int n0 = (nt&15)*64;
    int t = threadIdx.x;
    __shared__ __align__(16) u16 As[256*40];
    __shared__ __align__(16) u16 Bs[64*40];
    int w = t>>6, lane = t&63;
    int q = lane>>4, l16 = lane&15;
    int koff = q*8;
    int rA = t>>2, cA = t&3;      // A rows rA, rA+128 (rA 0..127); B row rA if t<256
    bool hasB = (t < 256);

    f4 acc[2][4];
    for(int mi=0;mi<2;mi++) for(int ni=0;ni<4;ni++){
        f4 z = {0.f,0.f,0.f,0.f}; acc[mi][ni] = z;
    }

    auto fetchB = [&](int k)->P8{
        int n = n0 + rA;
        if(k < 2048)       return fetch8(Wm, (size_t)n*I_ + k, isf32);
        else if(k < 3072)  return fetch8(Um, (size_t)n*H_ + (k-2048), isf32);
        else               return fetch8(Vm, (size_t)n*H_ + (k-3072), isf32);
    };

    uint4 qa0, qa1; P8 qb;
    qa0 = *(const uint4*)(Xc + (size_t)rA*4096       + k0 + cA*8);
    qa1 = *(const uint4*)(Xc + (size_t)(rA+128)*4096 + k0 + cA*8);
    if(hasB) qb = fetchB(k0 + cA*8);

    for(int ks=0; ks<512; ks+=32){
        __syncthreads();
        *(uint4*)&As[rA*40 + cA*8]       = qa0;
        *(uint4*)&As[(rA+128)*40 + cA*8] = qa1;
        if(hasB) *(uint4*)&Bs[rA*40 + cA*8] = cvt8(qb, isf32);
        __syncthreads();
        if(ks + 32 < 512){
            int kn = k0 + ks + 32;
            qa0 = *(const uint4*)(Xc + (size_t)rA*4096       + kn + cA*8);
            qa1 = *(const uint4*)(Xc + (size_t)(rA+128)*4096 + kn + cA*8);
            if(hasB) qb = fetchB(kn + cA*8);
        }
        bf8 af[2], bfr[4];
        for(int mi=0;mi<2;mi++) af[mi]  = *(const bf8*)&As[(w*32+mi*16+l16)*40 + koff];
        for(int ni=0;ni<4;ni++) bfr[ni] = *(const bf8*)&Bs[(ni*16+l16)*40 + koff];
        for(int mi=0;mi<2;mi++)
            for(int ni=0;ni<4;ni++)
                acc[mi][ni] = __builtin_amdgcn_mfma_f32_16x16x32_bf16(af[mi], bfr[ni], acc[mi][ni], 0,0,0);
    }
    float* pg = dosplit ? (part + ((size_t)kc*4 + g)*(size_t)(B_*H_))
                        : (part + (size_t)g*(B_*H_));
    for(int mi=0;mi<2;mi++){
        for(int r=0;r<4;r++){
            int brow = w*32 + mi*16 + q*4 + r;
            for(int ni=0;ni<4;ni++){
                int ncol = n0 + ni*16 + l16;
                size_t o = (size_t)brow*H_ + ncol;
                if(dosplit) pg[o] = acc[mi][ni][r];
                else        atomicAdd(&pg[o], acc[mi][ni][r]);
            }
        }
    }
}

// ---------------- combine: sum kc partials + f32 outputs ----------------
__global__ __launch_bounds__(256) void k_combine(const float* __restrict__ part,
    int nsplit, int climit,
    const void* __restrict__ c,
    const void* __restrict__ bi, const void* __restrict__ bfv,
    const void* __restrict__ bc, const void* __restrict__ bo,
    const int* __restrict__ flags,
    float* __restrict__ out){
    int b = blockIdx.x, t = threadIdx.x;
    int isf32 = flags[1];
    const size_t G = (size_t)B_*H_;
    for(int i=0;i<4;i++){
        int n = i*256 + t;
        size_t idx = (size_t)b*H_ + n;
        float pi = 0.f, pf = 0.f, pcv = 0.f, po = 0.f;
        for(int p=0;p<nsplit;p++){
            const float* pp = part + (size_t)p*4*G;
            pi += pp[idx];
            pf += pp[G + idx];
            po += pp[3*G + idx];
            if(p < climit) pcv += pp[2*G + idx];
        }
        pi  += loads(bi,  n, isf32);
        pf  += loads(bfv, n, isf32);
        pcv += loads(bc,  n, isf32);
        po  += loads(bo,  n, isf32);
        float ig = sigmoidf_(pi);
        float fg = sigmoidf_(pf);
        float og = sigmoidf_(po);
        float cold = loads(c, idx, isf32);
        float ncv = fg*cold + ig*fast_tanh(pcv);
        float nh  = og*fast_tanh(ncv);
        out[idx]     = nh;    // new_h
        out[G + idx] = ncv;   // new_c
    }
}

extern "C" void kernel_launch(void* const* d_in, const int* in_sizes, int n_in,
                              void* d_out, int out_size, void* d_ws, size_t ws_size,
                              hipStream_t stream){
    const void* xj   = d_in[0];
    const void* mask = d_in[1];
    const void* XF   = d_in[2];
    const void* h    = d_in[3];
    const void* c    = d_in[4];
    const void* Wi   = d_in[5];
    const void* Wf   = d_in[6];
    const void* Wc   = d_in[7];
    const void* Wo   = d_in[8];
    const void* Ui   = d_in[9];
    const void* Uf   = d_in[10];
    const void* Uc   = d_in[11];
    const void* Uo   = d_in[12];
    const void* Vi   = d_in[13];
    const void* Vf   = d_in[14];
    // d_in[15] = V_c : unused by the reference
    const void* Vo   = d_in[16];
    const void* bi   = d_in[17];
    const void* bfv  = d_in[18];
    const void* bc   = d_in[19];
    const void* bo   = d_in[20];
    const void* wv   = d_in[21];
    const void* We   = d_in[22];
    const void* Ue   = d_in[23];
    const void* be   = d_in[24];

    char* ws = (char*)d_ws;
    float* hwe  = (float*)(ws + HWE_OFF);
    u16*   Xc   = (u16*)(ws + XC_OFF);
    float* pre  = (float*)(ws + PRE_OFF);   // Epart during attention phase
    int*   flags= (int*)(ws + FLAG_OFF);
    float* out  = (float*)d_out;

    int big = (ws_size >= (size_t)WS_BIG);
    u16* ue16 = (u16*)(ws + UE16_OFF);
    float* gpart = (float*)(ws + GPART_OFF);
    const void* UeA = big ? (const void*)ue16 : Ue;

    k_detect<<<1, 256, 0, stream>>>((const u8*)mask, (const u16*)xj, flags);
    hipMemsetAsync(hwe, 0, (size_t)B_*Hh_*sizeof(float), stream);
    // pack (3584 blocks) + Ue bf16 conversion (256 blocks, big only)
    k_pack<<<3584 + (big ? 256 : 0), 256, 0, stream>>>(XF, h, c, Ue, flags, 3584, Xc, ue16);
    k_hwe<<<dim3(8,8,2), 256, 0, stream>>>(h, We, flags, hwe);
    k_attn<<<dim3(B_, 4), 512, 0, stream>>>(xj, wv, UeA, be, hwe, flags, big, pre);
    k_soft<<<B_, 512, 0, stream>>>(pre, mask, xj, flags, Xc);
    if(big){
        k_gates<<<dim3(64, 8), 512, 0, stream>>>(Xc, Wi,Wf,Wc,Wo, Ui,Uf,Uc,Uo, Vi,Vf,Vo, flags, 1, gpart);
        k_combine<<<B_, 256, 0, stream>>>(gpart, 8, 6, c, bi, bfv, bc, bo, flags, out);
    } else {
        hipMemsetAsync(pre, 0, (size_t)4*B_*H_*sizeof(float), stream);
        k_gates<<<dim3(64, 8), 512, 0, stream>>>(Xc, Wi,Wf,Wc,Wo, Ui,Uf,Uc,Uo, Vi,Vf,Vo, flags, 0, pre);
        k_combine<<<B_, 256, 0, stream>>>(pre, 1, 1, c, bi, bfv, bc, bo, flags, out);
    }
}

// Round 11
// 283.746 us; speedup vs baseline: 1.6544x; 1.0491x over previous
//
#include <hip/hip_runtime.h>
#include <hip/hip_bf16.h>

typedef unsigned char u8;
typedef unsigned short u16;
typedef unsigned int u32;
typedef __attribute__((ext_vector_type(8))) short bf8;
typedef __attribute__((ext_vector_type(4))) float f4;

#define B_ 256
#define O_ 128
#define Hh_ 512
#define H_ 1024
#define DF_ 1536
#define I_ 2048

// ws layout (bytes)
#define XC_OFF    524288     // 256*4096 bf16 = 2097152
#define PRE_OFF   2621440    // 4 MB region: Epart 512KB @ +0, hweP 2MB @ +1MB (attn phase);
                             // small-ws fallback: atomic pre (4MB) reuses region after soft
#define HWEP_OFF  (PRE_OFF + 1048576)
#define XJ16_OFF  7340032    // 32 MB region [big-ws only] — gpart
#define UE16_OFF  40894464   // 262144 bf16 = 524288       [big-ws only]
#define WS_BIG    41418752
#define GPART_OFF XJ16_OFF   // 8 kc * 4 gates * 256*1024 f32 = 33554432

__device__ __forceinline__ float bf1(u16 u){ union{u32 i; float f;} v; v.i = ((u32)u)<<16; return v.f; }
__device__ __forceinline__ u16 f2bf(float f){
    __hip_bfloat16 h = __float2bfloat16(f);
    union{ __hip_bfloat16 h; u16 u; } v; v.h = h; return v.u;
}
__device__ __forceinline__ u32 pack2(float a, float b){
    return ((u32)f2bf(a)) | (((u32)f2bf(b))<<16);
}
struct P8 { uint4 lo, hi; };
__device__ __forceinline__ P8 fetch8(const void* p, size_t idx, int isf32){
    P8 r;
    if(isf32){
        const uint4* f = (const uint4*)((const float*)p + idx);
        r.lo = f[0]; r.hi = f[1];
    } else {
        r.lo = *(const uint4*)((const u16*)p + idx);
    }
    return r;
}
__device__ __forceinline__ uint4 cvt8(P8 r, int isf32){
    if(isf32){
        float4 x = *(float4*)&r.lo, y = *(float4*)&r.hi;
        uint4 o;
        o.x = pack2(x.x,x.y); o.y = pack2(x.z,x.w);
        o.z = pack2(y.x,y.y); o.w = pack2(y.z,y.w);
        return o;
    }
    return r.lo;
}
__device__ __forceinline__ uint4 load8(const void* p, size_t idx, int isf32){
    return cvt8(fetch8(p, idx, isf32), isf32);
}
__device__ __forceinline__ float loads(const void* p, size_t idx, int isf32){
    return isf32 ? ((const float*)p)[idx] : bf1(((const u16*)p)[idx]);
}
__device__ __forceinline__ float fast_tanh(float x){
    return 1.0f - 2.0f/(__expf(2.0f*x)+1.0f);
}
__device__ __forceinline__ float sigmoidf_(float x){
    return 1.0f/(1.0f+__expf(-x));
}

// ---- per-block dtype detection (wave-uniform, deterministic, no global flags) ----
// xj f32 vs bf16: sample first 64 u16-pairs (256B). For f32, xj_u16[2i] is random
// low-mantissa bits -> (u>>7)&0xFF >= 156 with p~0.39/sample; for bf16 N(0,1) data
// the exponent never reaches 156. P(f32 miss over 64 samples) ~ 2e-14.
__device__ __forceinline__ int detect_isf32(const void* xj){
    int l = threadIdx.x & 63;
    u32 u = ((const u16*)xj)[2*l];
    int ex = (u>>7)&0xFF;
    unsigned long long m = __ballot(ex >= 156);
    return m != 0ULL;
}
// mask element width: sample first 64 u32 (256B). Same decision logic as the old
// k_detect, on a smaller (statistically safe) sample.
__device__ __forceinline__ int detect_mw(const void* maskp){
    int l = threadIdx.x & 63;
    u32 v = ((const u32*)maskp)[l];
    int b0 =  v      & 0xFF;
    int b1 = (v>>8)  & 0xFF;
    int b2 = (v>>16) & 0xFF;
    int b3 = (v>>24) & 0xFF;
    unsigned long long n1 = __ballot(b1 != 0);
    unsigned long long n2 = __ballot(b2 != 0);
    unsigned long long n3 = __ballot(b3 != 0);
    int mx = max(max(b0,b1), max(b2,b3));
    for(int s=32;s>0;s>>=1) mx = max(mx, __shfl_xor(mx, s));
    int w;
    if(!n1 && !n2 && !n3)      w = 4;   // int32
    else if(!n1 && n2 && n3)   w = 4;   // f32
    else if(mx > 1)            w = 2;   // bf16
    else                       w = 1;   // bool8
    return w;
}

// ---------------- merged prep: Ue->ue16 (big) | hweP GEMM | pack ----------------
// grid: [0, ueN)            Ue conversion (256 blocks, big only)
//       [ueN, ueN+64)       hwe GEMM partials: n=(r&7), kc=((r>>3)&3) of 256, m=(r>>5)
//       [ueN+64, +64+3584)  pack X_F|h|c -> Xc[512:4096) bf16
__global__ __launch_bounds__(256) void k_prep(const void* __restrict__ xj,
                                              const void* __restrict__ Ue,
                                              const void* __restrict__ XF,
                                              const void* __restrict__ h,
                                              const void* __restrict__ c,
                                              const void* __restrict__ We,
                                              int ueN,
                                              u16* __restrict__ ue16,
                                              float* __restrict__ hweP,
                                              u16* __restrict__ Xc){
    int bid = blockIdx.x, t = threadIdx.x;
    int isf32 = detect_isf32(xj);
    if(bid < ueN){
        size_t g = (size_t)bid*256 + t;
        size_t idx = g*8;                            // 524288 elems total
        *(uint4*)&ue16[idx] = load8(Ue, idx, isf32);
        return;
    }
    bid -= ueN;
    if(bid < 64){
        int n0 = (bid&7)*64;
        int kb = ((bid>>3)&3)*256;
        int m0 = (bid>>5)*128;
        __shared__ __align__(16) u16 As[128*40];
        __shared__ __align__(16) u16 Bs[64*40];
        int w = t>>6, lane = t&63;
        int q = lane>>4, l16 = lane&15;
        int koff = q*8;
        f4 acc[2][4];
        for(int mi=0;mi<2;mi++) for(int ni=0;ni<4;ni++){
            f4 z = {0.f,0.f,0.f,0.f}; acc[mi][ni] = z;
        }
        for(int ks=0; ks<256; ks+=32){
            __syncthreads();
            for(int i=0;i<2;i++){
                int row = i*64 + (t>>2), cv = t&3;
                uint4 va = load8(h, (size_t)(m0+row)*H_ + kb + ks + cv*8, isf32);
                *(uint4*)&As[row*40 + cv*8] = va;
            }
            {
                int row = t>>2, cv = t&3;
                uint4 vb = load8(We, (size_t)(n0+row)*H_ + kb + ks + cv*8, isf32);
                *(uint4*)&Bs[row*40 + cv*8] = vb;
            }
            __syncthreads();
            bf8 af[2], bfr[4];
            for(int mi=0;mi<2;mi++) af[mi]  = *(const bf8*)&As[(w*32+mi*16+l16)*40 + koff];
            for(int ni=0;ni<4;ni++) bfr[ni] = *(const bf8*)&Bs[(ni*16+l16)*40 + koff];
            for(int mi=0;mi<2;mi++)
                for(int ni=0;ni<4;ni++)
                    acc[mi][ni] = __builtin_amdgcn_mfma_f32_16x16x32_bf16(af[mi], bfr[ni], acc[mi][ni], 0,0,0);
        }
        float* hp = hweP + (size_t)((bid>>3)&3)*(B_*Hh_);
        for(int mi=0;mi<2;mi++){
            for(int r=0;r<4;r++){
                int brow = m0 + w*32 + mi*16 + q*4 + r;
                for(int ni=0;ni<4;ni++){
                    int ncol = n0 + ni*16 + l16;
                    hp[(size_t)brow*Hh_ + ncol] = acc[mi][ni][r];
                }
            }
        }
        return;
    }
    bid -= 64;
    {
        int b = bid/14;
        int r = (bid%14)*256 + t;   // 0..3583
        float v;
        if(r < DF_)            v = loads(XF, (size_t)b*DF_ + r, isf32);
        else if(r < DF_ + H_)  v = loads(h,  (size_t)b*H_ + (r - DF_), isf32);
        else                   v = loads(c,  (size_t)b*H_ + (r - DF_ - H_), isf32);
        Xc[(size_t)b*4096 + 512 + r] = f2bf(v);
    }
}

// ---------------- attention e-score GEMM: grid (256 b, 4 n-tiles of 128), 512 thr ----------------
// 8 waves/block; wave w owns 16 o-rows. hwe loaded as sum of 4 kc-partials.
__global__ __launch_bounds__(512) void k_attn(const void* __restrict__ xjA,
                                              const void* __restrict__ wvec,
                                              const void* __restrict__ UeA,
                                              const void* __restrict__ be,
                                              const float* __restrict__ hweP,
                                              int srcbfB,
                                              float* __restrict__ Epart){
    int b = blockIdx.x, y = blockIdx.y, t = threadIdx.x;
    int isf = detect_isf32(xjA);      // xj is always the raw input
    int isA = isf;
    int isB = srcbfB ? 0 : isf;       // UeA (bf16 master when big-ws)
    __shared__ __align__(16) u16 As[128*40];
    __shared__ __align__(16) u16 Bs[128*40];
    __shared__ float hwes[128];
    __shared__ float wvs[128];

    if(t < 128){
        int col = y*128 + t;
        float s = 0.f;
        #pragma unroll
        for(int p=0;p<4;p++) s += hweP[(size_t)p*(B_*Hh_) + (size_t)b*Hh_ + col];
        hwes[t] = s + loads(be, col, isf);
        wvs[t]  = loads(wvec, col, isf);
    }

    const size_t xboff = (size_t)b*O_*Hh_;
    int w = t>>6, lane = t&63;
    int q = lane>>4, l16 = lane&15;
    int koff = q*8;
    int rA = t>>2, cA = t&3;          // staging: row rA (0..127), chunk cA

    f4 acc[8];
    for(int ni=0;ni<8;ni++){
        f4 z = {0.f,0.f,0.f,0.f}; acc[ni] = z;
    }

    P8 pa, pb;
    pa = fetch8(xjA, xboff + (size_t)rA*Hh_        + cA*8, isA);
    pb = fetch8(UeA, (size_t)(y*128 + rA)*Hh_      + cA*8, isB);

    for(int ks=0; ks<Hh_; ks+=32){
        __syncthreads();
        *(uint4*)&As[rA*40 + cA*8] = cvt8(pa, isA);
        *(uint4*)&Bs[rA*40 + cA*8] = cvt8(pb, isB);
        __syncthreads();
        if(ks + 32 < Hh_){
            int kn = ks + 32;
            pa = fetch8(xjA, xboff + (size_t)rA*Hh_        + kn + cA*8, isA);
            pb = fetch8(UeA, (size_t)(y*128 + rA)*Hh_      + kn + cA*8, isB);
        }
        bf8 af, bfr[8];
        af = *(const bf8*)&As[(w*16+l16)*40 + koff];
        for(int ni=0;ni<8;ni++) bfr[ni] = *(const bf8*)&Bs[(ni*16+l16)*40 + koff];
        for(int ni=0;ni<8;ni++)
            acc[ni] = __builtin_amdgcn_mfma_f32_16x16x32_bf16(af, bfr[ni], acc[ni], 0,0,0);
    }
    // epilogue: wave w owns o-rows w*16..w*16+15 -> plain stores, no atomics
    for(int r=0;r<4;r++){
        int o = w*16 + q*4 + r;
        float part = 0.f;
        for(int ni=0;ni<8;ni++){
            int col = ni*16 + l16;
            part += wvs[col] * fast_tanh(hwes[col] + acc[ni][r]);
        }
        part += __shfl_xor(part, 1);
        part += __shfl_xor(part, 2);
        part += __shfl_xor(part, 4);
        part += __shfl_xor(part, 8);
        if(l16 == 0) Epart[(size_t)y*32768 + (size_t)b*O_ + o] = part;
    }
}

// ---------------- softmax + phi: grid 256 (per b), 512 thr ----------------
__global__ __launch_bounds__(512) void k_soft(const float* __restrict__ Epart,
                                              const void* __restrict__ maskp,
                                              const void* __restrict__ xjA,
                                              u16* __restrict__ Xc){
    int b = blockIdx.x, t = threadIdx.x;
    int isf = detect_isf32(xjA);
    int isA = isf;
    int mw = detect_mw(maskp);
    __shared__ float es[O_];
    __shared__ float as_[O_];
    __shared__ float red[2];
    if(t < O_){
        float e = 0.f;
        for(int p=0;p<4;p++) e += Epart[(size_t)p*32768 + (size_t)b*O_ + t];
        size_t mi_ = (size_t)b*O_ + t;
        bool valid;
        if(mw == 1)      valid = ((const u8*)maskp)[mi_]  != 0;
        else if(mw == 2) valid = ((const u16*)maskp)[mi_] != 0;
        else             valid = ((const u32*)maskp)[mi_] != 0;
        es[t] = valid ? e : -1e30f;
    }
    __syncthreads();
    if(t < 64){
        float v = fmaxf(es[t], es[t+64]);
        for(int m=32;m>0;m>>=1) v = fmaxf(v, __shfl_xor(v, m));
        if(t==0) red[0] = v;
    }
    __syncthreads();
    if(t < O_) as_[t] = __expf(es[t] - red[0]);
    __syncthreads();
    if(t < 64){
        float v = as_[t] + as_[t+64];
        for(int m=32;m>0;m>>=1) v += __shfl_xor(v, m);
        if(t==0) red[1] = v;
    }
    __syncthreads();
    float inv = 1.0f / red[1];
    float acc = 0.f;
    size_t base = (size_t)b*O_*Hh_ + t;
    #pragma unroll 8
    for(int o=0;o<O_;o++){
        acc += as_[o] * loads(xjA, base + (size_t)o*Hh_, isA);
    }
    Xc[(size_t)b*4096 + t] = f2bf(acc * inv);
}

// ---------------- gates GEMM, K-split: grid (64 nt, 8 kc of 512), 512 thr, BK=32 ----------------
__global__ __launch_bounds__(512) void k_gates(const u16* __restrict__ Xc,
    const void* __restrict__ xjdet,
    const void* __restrict__ Wi, const void* __restrict__ Wf, const void* __restrict__ Wc, const void* __restrict__ Wo,
    const void* __restrict__ Ui, const void* __restrict__ Uf, const void* __restrict__ Uc, const void* __restrict__ Uo,
    const void* __restrict__ Vi, const void* __restrict__ Vf, const void* __restrict__ Vo,
    int dosplit,
    float* __restrict__ part){
    int nt = blockIdx.x;          // gate g = nt>>4, n-tile nt&15
    int kc = blockIdx.y;          // K-chunk of 512
    int g  = nt>>4;
    int k0 = kc*512;
    if(g == 2 && k0 >= 3072) return; // c-gate has no V peephole
    int isf32 = detect_isf32(xjdet);
    const void* Wm = (g==0)?Wi:(g==1)?Wf:(g==2)?Wc:Wo;
    const void* Um = (g==0)?Ui:(g==1)?Uf:(g==2)?Uc:Uo;
    const void* Vm = (g==0)?Vi:(g==1)?Vf:(g==3)?Vo:Vi;  // g==2 never dereferences V
    int n0 = (nt&15)*64;
    int t = threadIdx.x;
    __shared__ __align__(16) u16 As[256*40];
    __shared__ __align__(16) u16 Bs[64*40];
    int w = t>>6, lane = t&63;
    int q = lane>>4, l16 = lane&15;
    int koff = q*8;
    int rA = t>>2, cA = t&3;      // A rows rA, rA+128 (rA 0..127); B row rA if t<256
    bool hasB = (t < 256);

    f4 acc[2][4];
    for(int mi=0;mi<2;mi++) for(int ni=0;ni<4;ni++){
        f4 z = {0.f,0.f,0.f,0.f}; acc[mi][ni] = z;
    }

    auto fetchB = [&](int k)->P8{
        int n = n0 + rA;
        if(k < 2048)       return fetch8(Wm, (size_t)n*I_ + k, isf32);
        else if(k < 3072)  return fetch8(Um, (size_t)n*H_ + (k-2048), isf32);
        else               return fetch8(Vm, (size_t)n*H_ + (k-3072), isf32);
    };

    uint4 qa0, qa1; P8 qb;
    qa0 = *(const uint4*)(Xc + (size_t)rA*4096       + k0 + cA*8);
    qa1 = *(const uint4*)(Xc + (size_t)(rA+128)*4096 + k0 + cA*8);
    if(hasB) qb = fetchB(k0 + cA*8);

    for(int ks=0; ks<512; ks+=32){
        __syncthreads();
        *(uint4*)&As[rA*40 + cA*8]       = qa0;
        *(uint4*)&As[(rA+128)*40 + cA*8] = qa1;
        if(hasB) *(uint4*)&Bs[rA*40 + cA*8] = cvt8(qb, isf32);
        __syncthreads();
        if(ks + 32 < 512){
            int kn = k0 + ks + 32;
            qa0 = *(const uint4*)(Xc + (size_t)rA*4096       + kn + cA*8);
            qa1 = *(const uint4*)(Xc + (size_t)(rA+128)*4096 + kn + cA*8);
            if(hasB) qb = fetchB(kn + cA*8);
        }
        bf8 af[2], bfr[4];
        for(int mi=0;mi<2;mi++) af[mi]  = *(const bf8*)&As[(w*32+mi*16+l16)*40 + koff];
        for(int ni=0;ni<4;ni++) bfr[ni] = *(const bf8*)&Bs[(ni*16+l16)*40 + koff];
        for(int mi=0;mi<2;mi++)
            for(int ni=0;ni<4;ni++)
                acc[mi][ni] = __builtin_amdgcn_mfma_f32_16x16x32_bf16(af[mi], bfr[ni], acc[mi][ni], 0,0,0);
    }
    float* pg = dosplit ? (part + ((size_t)kc*4 + g)*(size_t)(B_*H_))
                        : (part + (size_t)g*(B_*H_));
    for(int mi=0;mi<2;mi++){
        for(int r=0;r<4;r++){
            int brow = w*32 + mi*16 + q*4 + r;
            for(int ni=0;ni<4;ni++){
                int ncol = n0 + ni*16 + l16;
                size_t o = (size_t)brow*H_ + ncol;
                if(dosplit) pg[o] = acc[mi][ni][r];
                else        atomicAdd(&pg[o], acc[mi][ni][r]);
            }
        }
    }
}

// ---------------- combine: sum kc partials + f32 outputs ----------------
__global__ __launch_bounds__(256) void k_combine(const float* __restrict__ part,
    int nsplit, int climit,
    const void* __restrict__ xjdet,
    const void* __restrict__ c,
    const void* __restrict__ bi, const void* __restrict__ bfv,
    const void* __restrict__ bc, const void* __restrict__ bo,
    float* __restrict__ out){
    int b = blockIdx.x, t = threadIdx.x;
    int isf32 = detect_isf32(xjdet);
    const size_t G = (size_t)B_*H_;
    for(int i=0;i<4;i++){
        int n = i*256 + t;
        size_t idx = (size_t)b*H_ + n;
        float pi = 0.f, pf = 0.f, pcv = 0.f, po = 0.f;
        for(int p=0;p<nsplit;p++){
            const float* pp = part + (size_t)p*4*G;
            pi += pp[idx];
            pf += pp[G + idx];
            po += pp[3*G + idx];
            if(p < climit) pcv += pp[2*G + idx];
        }
        pi  += loads(bi,  n, isf32);
        pf  += loads(bfv, n, isf32);
        pcv += loads(bc,  n, isf32);
        po  += loads(bo,  n, isf32);
        float ig = sigmoidf_(pi);
        float fg = sigmoidf_(pf);
        float og = sigmoidf_(po);
        float cold = loads(c, idx, isf32);
        float ncv = fg*cold + ig*fast_tanh(pcv);
        float nh  = og*fast_tanh(ncv);
        out[idx]     = nh;    // new_h
        out[G + idx] = ncv;   // new_c
    }
}

extern "C" void kernel_launch(void* const* d_in, const int* in_sizes, int n_in,
                              void* d_out, int out_size, void* d_ws, size_t ws_size,
                              hipStream_t stream){
    const void* xj   = d_in[0];
    const void* mask = d_in[1];
    const void* XF   = d_in[2];
    const void* h    = d_in[3];
    const void* c    = d_in[4];
    const void* Wi   = d_in[5];
    const void* Wf   = d_in[6];
    const void* Wc   = d_in[7];
    const void* Wo   = d_in[8];
    const void* Ui   = d_in[9];
    const void* Uf   = d_in[10];
    const void* Uc   = d_in[11];
    const void* Uo   = d_in[12];
    const void* Vi   = d_in[13];
    const void* Vf   = d_in[14];
    // d_in[15] = V_c : unused by the reference
    const void* Vo   = d_in[16];
    const void* bi   = d_in[17];
    const void* bfv  = d_in[18];
    const void* bc   = d_in[19];
    const void* bo   = d_in[20];
    const void* wv   = d_in[21];
    const void* We   = d_in[22];
    const void* Ue   = d_in[23];
    const void* be   = d_in[24];

    char* ws = (char*)d_ws;
    u16*   Xc    = (u16*)(ws + XC_OFF);
    float* Epart = (float*)(ws + PRE_OFF);
    float* hweP  = (float*)(ws + HWEP_OFF);
    float* pre   = (float*)(ws + PRE_OFF);   // small-ws fallback atomic buffer
    float* out   = (float*)d_out;

    int big = (ws_size >= (size_t)WS_BIG);
    u16* ue16 = (u16*)(ws + UE16_OFF);
    float* gpart = (float*)(ws + GPART_OFF);
    const void* UeA = big ? (const void*)ue16 : Ue;

    int ueN = big ? 256 : 0;
    k_prep<<<ueN + 64 + 3584, 256, 0, stream>>>(xj, Ue, XF, h, c, We, ueN, ue16, hweP, Xc);
    k_attn<<<dim3(B_, 4), 512, 0, stream>>>(xj, wv, UeA, be, hweP, big, Epart);
    k_soft<<<B_, 512, 0, stream>>>(Epart, mask, xj, Xc);
    if(big){
        k_gates<<<dim3(64, 8), 512, 0, stream>>>(Xc, xj, Wi,Wf,Wc,Wo, Ui,Uf,Uc,Uo, Vi,Vf,Vo, 1, gpart);
        k_combine<<<B_, 256, 0, stream>>>(gpart, 8, 6, xj, c, bi, bfv, bc, bo, out);
    } else {
        hipMemsetAsync(pre, 0, (size_t)4*B_*H_*sizeof(float), stream);
        k_gates<<<dim3(64, 8), 512, 0, stream>>>(Xc, xj, Wi,Wf,Wc,Wo, Ui,Uf,Uc,Uo, Vi,Vf,Vo, 0, pre);
        k_combine<<<B_, 256, 0, stream>>>(pre, 1, 1, xj, c, bi, bfv, bc, bo, out);
    }
}